// Round 18
// baseline (324.863 us; speedup 1.0000x reference)
//
#include <hip/hip_runtime.h>

#define OUT_ZQ   0
#define OUT_DIFF 2097152
#define OUT_IND  2097153

// ws layout (bytes) — big path total 17,993,728 <= proven 18,087,936
#define WS_AMIN   0        // u64[8192]                     [0        .. 65536)
#define WS_A      65536    // f32[8192]                     [65536    .. 98304)
#define WS_N      98304    // f32[8192]                     [98304    .. 131072)
#define WS_THR    131072   // f32[8192]                     [131072   .. 163840)
#define WS_PART   163840   // f32[1024]                     [163840   .. 167936)
#define WS_BV1    167936   // f32[8][8192] = 262144         [167936   .. 430080)
#define WS_BI1    430080   // u16[8][8192] = 131072         [430080   .. 561152)
#define WS_BV2    561152   // f32[8][8192] = 262144         [561152   .. 823296)
#define WS_BI2    823296   // u16[8][8192] = 131072         [823296   .. 954368)
#define WS_B3V    954368   // f32[8][8192] = 262144         [954368   .. 1216512)
#define WS_ZH3    1216512  // u16[2M] = 4 MB fragment-major [1216512  .. 5410816)
#define WS_ZL3    5410816  //                                [5410816  .. 9605120)
#define WS_EH3    9605120  //                                [9605120  .. 13799424)
#define WS_EL3    13799424 //                                [13799424 .. 17993728)
#define WS_BIG_END 17993728ULL

typedef unsigned long long u64t;
typedef __attribute__((ext_vector_type(8))) short bf16x8;
typedef __attribute__((ext_vector_type(4))) float f32x4;

__device__ inline unsigned short bf16rn(float f) {
    unsigned u = __float_as_uint(f);
    return (unsigned short)((u + 0x7fffu + ((u >> 16) & 1u)) >> 16);
}
__device__ inline float bf16tof(unsigned short h) { return __uint_as_float(((unsigned)h) << 16); }
__device__ inline float valf(u64t k) { return __uint_as_float((unsigned)(k >> 32)); }

#define INITKEY ((((u64t)0x7F7FFFFFu) << 32) | 0xFFFFu)   // value = FLT_MAX (no NaN)

// ---------------------------------------------------------------- z_e: bit-exact np.einsum replica (r15-proven v2)
__global__ __launch_bounds__(256) void k_ze_np(const float* __restrict__ z,
                                               const float* __restrict__ pw,
                                               const float* __restrict__ pb,
                                               float* __restrict__ ze) {
    __shared__ float lz[32][16];
    const int t   = threadIdx.x;
    const int b   = blockIdx.x >> 6;
    const int hw0 = (blockIdx.x & 63) * 16;

    float acc[16];
#pragma unroll
    for (int p = 0; p < 16; ++p) acc[p] = 0.0f;

    for (int cc = 0; cc < 256; cc += 32) {
        float4 wv[8];
        const float4* wsrc = reinterpret_cast<const float4*>(pw + (size_t)t * 256 + cc);
#pragma unroll
        for (int i = 0; i < 8; ++i) wv[i] = wsrc[i];
        float zv[2];
#pragma unroll
        for (int i = 0; i < 2; ++i) {
            const int f = t + i * 256;
            zv[i] = z[(size_t)(b * 256 + cc + (f >> 4)) * 1024 + hw0 + (f & 15)];
        }
        __syncthreads();
#pragma unroll
        for (int i = 0; i < 2; ++i) {
            const int f = t + i * 256;
            lz[f >> 4][f & 15] = zv[i];
        }
        __syncthreads();
#define ZSTEP(CL, WL) {                                                     \
    const float4 q0 = *reinterpret_cast<const float4*>(&lz[CL][0]);         \
    const float4 q1 = *reinterpret_cast<const float4*>(&lz[CL][4]);         \
    const float4 q2 = *reinterpret_cast<const float4*>(&lz[CL][8]);         \
    const float4 q3 = *reinterpret_cast<const float4*>(&lz[CL][12]);        \
    acc[0]  = __fadd_rn(acc[0],  __fmul_rn(q0.x, WL));                      \
    acc[1]  = __fadd_rn(acc[1],  __fmul_rn(q0.y, WL));                      \
    acc[2]  = __fadd_rn(acc[2],  __fmul_rn(q0.z, WL));                      \
    acc[3]  = __fadd_rn(acc[3],  __fmul_rn(q0.w, WL));                      \
    acc[4]  = __fadd_rn(acc[4],  __fmul_rn(q1.x, WL));                      \
    acc[5]  = __fadd_rn(acc[5],  __fmul_rn(q1.y, WL));                      \
    acc[6]  = __fadd_rn(acc[6],  __fmul_rn(q1.z, WL));                      \
    acc[7]  = __fadd_rn(acc[7],  __fmul_rn(q1.w, WL));                      \
    acc[8]  = __fadd_rn(acc[8],  __fmul_rn(q2.x, WL));                      \
    acc[9]  = __fadd_rn(acc[9],  __fmul_rn(q2.y, WL));                      \
    acc[10] = __fadd_rn(acc[10], __fmul_rn(q2.z, WL));                      \
    acc[11] = __fadd_rn(acc[11], __fmul_rn(q2.w, WL));                      \
    acc[12] = __fadd_rn(acc[12], __fmul_rn(q3.x, WL));                      \
    acc[13] = __fadd_rn(acc[13], __fmul_rn(q3.y, WL));                      \
    acc[14] = __fadd_rn(acc[14], __fmul_rn(q3.z, WL));                      \
    acc[15] = __fadd_rn(acc[15], __fmul_rn(q3.w, WL)); }
#pragma unroll
        for (int c8 = 0; c8 < 8; ++c8) {
            const float4 wq = wv[c8];
            ZSTEP(c8 * 4 + 0, wq.x)
            ZSTEP(c8 * 4 + 1, wq.y)
            ZSTEP(c8 * 4 + 2, wq.z)
            ZSTEP(c8 * 4 + 3, wq.w)
        }
#undef ZSTEP
    }
    const float bb = pb[t];
#pragma unroll
    for (int p = 0; p < 16; ++p)
        ze[(size_t)(b * 1024 + hw0 + p) * 256 + t] = __fadd_rn(acc[p], bb);
}

// ---------------------------------------------------------------- np pairwise row-norms
__global__ __launch_bounds__(256) void k_rowstats(const float* __restrict__ ze,
                                                  const float* __restrict__ embed,
                                                  float* __restrict__ A,
                                                  float* __restrict__ Nf) {
    const int gid = blockIdx.x * 256 + threadIdx.x;
    const float* row = (gid < 8192) ? (ze + (size_t)gid * 256)
                                    : (embed + (size_t)(gid - 8192) * 256);
    float blk[2];
#pragma unroll
    for (int half = 0; half < 2; ++half) {
        const float4* r4 = reinterpret_cast<const float4*>(row + half * 128);
        float r[8];
#pragma unroll
        for (int i = 0; i < 16; ++i) {
            const float4 a = r4[i * 2], b = r4[i * 2 + 1];
            const float s[8] = {__fmul_rn(a.x, a.x), __fmul_rn(a.y, a.y),
                                __fmul_rn(a.z, a.z), __fmul_rn(a.w, a.w),
                                __fmul_rn(b.x, b.x), __fmul_rn(b.y, b.y),
                                __fmul_rn(b.z, b.z), __fmul_rn(b.w, b.w)};
            if (i == 0) {
#pragma unroll
                for (int j = 0; j < 8; ++j) r[j] = s[j];
            } else {
#pragma unroll
                for (int j = 0; j < 8; ++j) r[j] = __fadd_rn(r[j], s[j]);
            }
        }
        blk[half] = __fadd_rn(__fadd_rn(__fadd_rn(r[0], r[1]), __fadd_rn(r[2], r[3])),
                              __fadd_rn(__fadd_rn(r[4], r[5]), __fadd_rn(r[6], r[7])));
    }
    const float res = __fadd_rn(blk[0], blk[1]);
    if (gid < 8192) A[gid] = res;
    else            Nf[gid - 8192] = res;
}

// ---------------------------------------------------------------- bf16 hi/lo precompute in FRAGMENT-MAJOR layout (r15-proven)
__global__ __launch_bounds__(256) void k_cvt(const float* __restrict__ ze,
                                             const float* __restrict__ embed,
                                             unsigned short* __restrict__ zh3,
                                             unsigned short* __restrict__ zl3,
                                             unsigned short* __restrict__ eh3,
                                             unsigned short* __restrict__ el3) {
    const int gid = blockIdx.x * 256 + threadIdx.x;
    const int row = gid >> 5;
    const int c0  = (gid & 31) * 8;
    const bool isz = (row < 8192);
    const float* src = (isz ? ze + (size_t)row * 256 : embed + (size_t)(row - 8192) * 256) + c0;
    const float4 v0 = reinterpret_cast<const float4*>(src)[0];
    const float4 v1 = reinterpret_cast<const float4*>(src)[1];
    float x[8] = {v0.x, v0.y, v0.z, v0.w, v1.x, v1.y, v1.z, v1.w};
    if (isz) {
#pragma unroll
        for (int i = 0; i < 8; ++i) x[i] = __fmul_rn(2.0f, x[i]);   // exact prescale
    }
    unsigned short hv[8], lv[8];
#pragma unroll
    for (int i = 0; i < 8; ++i) {
        hv[i] = bf16rn(x[i]);
        lv[i] = bf16rn(__fsub_rn(x[i], bf16tof(hv[i])));
    }
    const int ci = c0 >> 5, lg = (c0 >> 3) & 3;
    if (isz) {
        const int pt = row >> 6, ti = (row >> 4) & 3, lr = row & 15;
        const int lane = lg * 16 + lr;
        const size_t off = ((size_t)(ci * 128 + pt) * 4 + ti) * 512 + (size_t)lane * 8;
        *reinterpret_cast<ushort4*>(zh3 + off)     = make_ushort4(hv[0], hv[1], hv[2], hv[3]);
        *reinterpret_cast<ushort4*>(zh3 + off + 4) = make_ushort4(hv[4], hv[5], hv[6], hv[7]);
        *reinterpret_cast<ushort4*>(zl3 + off)     = make_ushort4(lv[0], lv[1], lv[2], lv[3]);
        *reinterpret_cast<ushort4*>(zl3 + off + 4) = make_ushort4(lv[4], lv[5], lv[6], lv[7]);
    } else {
        const int k = row - 8192;
        const int kblk = k >> 8, w = (k >> 6) & 3, tj = (k >> 4) & 3, lr = k & 15;
        const int lane = lg * 16 + lr;
        const size_t off = (((size_t)(kblk * 8 + ci) * 16) + w * 4 + tj) * 512 + (size_t)lane * 8;
        *reinterpret_cast<ushort4*>(eh3 + off)     = make_ushort4(hv[0], hv[1], hv[2], hv[3]);
        *reinterpret_cast<ushort4*>(eh3 + off + 4) = make_ushort4(hv[4], hv[5], hv[6], hv[7]);
        *reinterpret_cast<ushort4*>(el3 + off)     = make_ushort4(lv[0], lv[1], lv[2], lv[3]);
        *reinterpret_cast<ushort4*>(el3 + off + 4) = make_ushort4(lv[4], lv[5], lv[6], lv[7]);
    }
}

// ---------------------------------------------------------------- MFMA screen v4: 8 k-splits (grid 1024 = 4 blocks/CU)
__global__ __launch_bounds__(256, 2) void k_mfma(const float* __restrict__ A,
                                                 const float* __restrict__ Nf,
                                                 const unsigned short* __restrict__ zh3,
                                                 const unsigned short* __restrict__ zl3,
                                                 const unsigned short* __restrict__ eh3,
                                                 const unsigned short* __restrict__ el3,
                                                 float* __restrict__ bv1,
                                                 unsigned short* __restrict__ bi1,
                                                 float* __restrict__ bv2,
                                                 unsigned short* __restrict__ bi2,
                                                 float* __restrict__ b3v) {
    __shared__ u64t  mrgk[64][4][2];
    __shared__ float mrgv[64][4];
    const int t = threadIdx.x;
    const int ks = blockIdx.x & 7, pt = blockIdx.x >> 3;
    const int pix0 = pt * 64;
    const int w = t >> 6, l = t & 63;
    const int lg = l >> 4, lr = l & 15;

    float a_reg[4][4];
#pragma unroll
    for (int ti = 0; ti < 4; ++ti)
#pragma unroll
        for (int r = 0; r < 4; ++r)
            a_reg[ti][r] = A[pix0 + ti * 16 + lg * 4 + r];

    u64t b1[4][4], b2[4][4];
    float bv[4][4];
#pragma unroll
    for (int ti = 0; ti < 4; ++ti)
#pragma unroll
        for (int r = 0; r < 4; ++r) { b1[ti][r] = INITKEY; b2[ti][r] = INITKEY; bv[ti][r] = 3.402823466e+38f; }

    const size_t zoff0 = (size_t)pt * 2048 + (size_t)l * 8;
    for (int ksub = 0; ksub < 4; ++ksub) {
        f32x4 acc[4][4];
#pragma unroll
        for (int ti = 0; ti < 4; ++ti)
#pragma unroll
            for (int tj = 0; tj < 4; ++tj) acc[ti][tj] = (f32x4)(0.0f);

        const size_t ebase = (size_t)(ks * 4 + ksub) * 65536 + (size_t)w * 2048 + (size_t)l * 8;
#pragma unroll 2
        for (int ci = 0; ci < 8; ++ci) {
            const size_t zo = zoff0 + (size_t)ci * 262144;
            const size_t eo = ebase + (size_t)ci * 8192;
            bf16x8 az[4], alz[4], be[4], ble[4];
#pragma unroll
            for (int ti = 0; ti < 4; ++ti) {
                az[ti]  = *reinterpret_cast<const bf16x8*>(zh3 + zo + (size_t)ti * 512);
                alz[ti] = *reinterpret_cast<const bf16x8*>(zl3 + zo + (size_t)ti * 512);
            }
#pragma unroll
            for (int tj = 0; tj < 4; ++tj) {
                be[tj]  = *reinterpret_cast<const bf16x8*>(eh3 + eo + (size_t)tj * 512);
                ble[tj] = *reinterpret_cast<const bf16x8*>(el3 + eo + (size_t)tj * 512);
            }
#pragma unroll
            for (int tj = 0; tj < 4; ++tj)
#pragma unroll
                for (int ti = 0; ti < 4; ++ti) {
                    acc[ti][tj] = __builtin_amdgcn_mfma_f32_16x16x32_bf16(az[ti],  be[tj],  acc[ti][tj], 0, 0, 0);
                    acc[ti][tj] = __builtin_amdgcn_mfma_f32_16x16x32_bf16(az[ti],  ble[tj], acc[ti][tj], 0, 0, 0);
                    acc[ti][tj] = __builtin_amdgcn_mfma_f32_16x16x32_bf16(alz[ti], be[tj],  acc[ti][tj], 0, 0, 0);
                }
        }
#pragma unroll
        for (int tj = 0; tj < 4; ++tj) {
            const int kk = ks * 1024 + ksub * 256 + w * 64 + tj * 16 + lr;
            const float nk = Nf[kk];
#pragma unroll
            for (int ti = 0; ti < 4; ++ti)
#pragma unroll
                for (int r = 0; r < 4; ++r) {
                    const float vv = __fadd_rn(__fsub_rn(a_reg[ti][r], acc[ti][tj][r]), nk);
                    const u64t key = ((u64t)__float_as_uint(vv) << 32) | (unsigned)kk;
                    if (key < b2[ti][r]) {
                        bv[ti][r] = valf(b2[ti][r]);
                        if (key < b1[ti][r]) { b2[ti][r] = b1[ti][r]; b1[ti][r] = key; }
                        else                 { b2[ti][r] = key; }
                    } else {
                        bv[ti][r] = fminf(bv[ti][r], vv);
                    }
                }
        }
    }
#pragma unroll
    for (int ti = 0; ti < 4; ++ti)
#pragma unroll
        for (int r = 0; r < 4; ++r) {
            u64t k1 = b1[ti][r], k2 = b2[ti][r];
            float v3 = bv[ti][r];
#pragma unroll
            for (int m = 1; m <= 8; m <<= 1) {
                const u64t o1 = __shfl_xor(k1, m, 64);
                const u64t o2 = __shfl_xor(k2, m, 64);
                const float ov = __shfl_xor(v3, m, 64);
                const u64t n1 = (k1 < o1) ? k1 : o1;
                const u64t X  = (k1 < o1) ? o1 : k1;
                const u64t Y  = (k2 < o2) ? k2 : o2;
                const u64t n2 = (X < Y) ? X : Y;
                const u64t t4 = (X < Y) ? Y : X;
                v3 = fminf(fminf(v3, ov), valf(t4));
                k1 = n1; k2 = n2;
            }
            b1[ti][r] = k1; b2[ti][r] = k2; bv[ti][r] = v3;
        }
    if (lr == 0) {
#pragma unroll
        for (int ti = 0; ti < 4; ++ti)
#pragma unroll
            for (int r = 0; r < 4; ++r) {
                const int pxl = ti * 16 + lg * 4 + r;
                mrgk[pxl][w][0] = b1[ti][r];
                mrgk[pxl][w][1] = b2[ti][r];
                mrgv[pxl][w]    = bv[ti][r];
            }
    }
    __syncthreads();
    if (t < 64) {
        u64t K1 = INITKEY, K2 = INITKEY;
        float V3 = 3.402823466e+38f;
#pragma unroll
        for (int w4 = 0; w4 < 4; ++w4) {
            const u64t o1 = mrgk[t][w4][0], o2 = mrgk[t][w4][1];
            const float ov = mrgv[t][w4];
            const u64t n1 = (K1 < o1) ? K1 : o1;
            const u64t X  = (K1 < o1) ? o1 : K1;
            const u64t Y  = (K2 < o2) ? K2 : o2;
            const u64t n2 = (X < Y) ? X : Y;
            const u64t t4 = (X < Y) ? Y : X;
            V3 = fminf(fminf(V3, ov), valf(t4));
            K1 = n1; K2 = n2;
        }
        const size_t o = (size_t)ks * 8192 + pix0 + t;
        bv1[o] = valf(K1);
        bi1[o] = (unsigned short)(K1 & 0xffffu);
        bv2[o] = valf(K2);
        bi2[o] = (unsigned short)(K2 & 0xffffu);
        b3v[o] = V3;
    }
}

// ---------------------------------------------------------------- np-exact candidate rescore (inline chain, r5-proven)
__device__ inline u64t np_score(const float* __restrict__ ze,
                                const float* __restrict__ embed,
                                const float a, const float* __restrict__ Nf,
                                const int px, const int k) {
    const float4* zr = reinterpret_cast<const float4*>(ze + (size_t)px * 256);
    const float4* er = reinterpret_cast<const float4*>(embed + (size_t)k * 256);
    float acc = 0.0f;
    for (int c4 = 0; c4 < 64; ++c4) {
        const float4 z4 = zr[c4], e4 = er[c4];
        acc = fmaf(__fmul_rn(2.0f, z4.x), e4.x, acc);
        acc = fmaf(__fmul_rn(2.0f, z4.y), e4.y, acc);
        acc = fmaf(__fmul_rn(2.0f, z4.z), e4.z, acc);
        acc = fmaf(__fmul_rn(2.0f, z4.w), e4.w, acc);
    }
    const float v = __fadd_rn(__fsub_rn(a, acc), Nf[k]);
    return ((u64t)__float_as_uint(v) << 32) | (unsigned)k;
}

// ---------------------------------------------------------------- select+rescore: thresh, in-window candidates, amin store
__global__ __launch_bounds__(256) void k_selres(const float* __restrict__ ze,
                                                const float* __restrict__ embed,
                                                const float* __restrict__ A,
                                                const float* __restrict__ Nf,
                                                const float* __restrict__ bv1,
                                                const unsigned short* __restrict__ bi1,
                                                const float* __restrict__ bv2,
                                                const unsigned short* __restrict__ bi2,
                                                float* __restrict__ thr,
                                                u64t* __restrict__ amin) {
    const int px = blockIdx.x * 256 + threadIdx.x;
    float m = bv1[px];
#pragma unroll
    for (int s = 1; s < 8; ++s) m = fminf(m, bv1[(size_t)s * 8192 + px]);
    const float a = A[px];
    const unsigned eb = (__float_as_uint(a + 0.125f) >> 23) & 255u;
    const float up = __uint_as_float((eb - 23u) << 23);
    const float thresh = m + 4.5f * up + 1.0e-5f;
    thr[px] = thresh;

    u64t best = ~0ULL;
#pragma unroll
    for (int s = 0; s < 8; ++s) {
        const size_t o = (size_t)s * 8192 + px;
        if (bv1[o] <= thresh) {
            const u64t key = np_score(ze, embed, a, Nf, px, (int)(bi1[o] & 8191u));
            best = (key < best) ? key : best;
        }
        if (bv2[o] <= thresh) {
            const u64t key = np_score(ze, embed, a, Nf, px, (int)(bi2[o] & 8191u));
            best = (key < best) ? key : best;
        }
    }
    amin[px] = best;   // winning split's v1 = m <= thresh, so best is always valid
}

// ---------------------------------------------------------------- deep v4: scan items (px,s,slice), process hits
__global__ __launch_bounds__(256) void k_deep(const float* __restrict__ ze,
                                              const float* __restrict__ embed,
                                              const float* __restrict__ A,
                                              const float* __restrict__ Nf,
                                              const float* __restrict__ thr,
                                              const float* __restrict__ b3v,
                                              u64t* __restrict__ amin) {
    __shared__ float lz2[256];
    __shared__ float sa[1];
    __shared__ u64t lw4[4];
    __shared__ int list[128];
    __shared__ int nact;
    const int t = threadIdx.x;
    const int base = blockIdx.x * 128;   // 2048 blocks x 128 = 262144 items

    if (t == 0) nact = 0;
    __syncthreads();
    if (t < 128) {
        const int it = base + t;
        const int px = it >> 5, s = (it >> 2) & 7;
        if (b3v[(size_t)s * 8192 + px] <= thr[px]) {
            const int p = atomicAdd(&nact, 1);
            list[p] = it;
        }
    }
    __syncthreads();
    const int n = nact;
    for (int i = 0; i < n; ++i) {
        const int it = list[i];
        const int px = it >> 5, s = (it >> 2) & 7, slice = it & 3;
        __syncthreads();
        lz2[t] = __fmul_rn(2.0f, ze[(size_t)px * 256 + t]);   // exact prescale
        if (t == 0) sa[0] = A[px];
        __syncthreads();
        const int k = s * 1024 + slice * 256 + t;
        const float4* er = reinterpret_cast<const float4*>(embed + (size_t)k * 256);
        float acc = 0.0f;
#pragma unroll 8
        for (int c4 = 0; c4 < 64; ++c4) {
            const float4 e4 = er[c4];
            acc = fmaf(lz2[c4 * 4 + 0], e4.x, acc);
            acc = fmaf(lz2[c4 * 4 + 1], e4.y, acc);
            acc = fmaf(lz2[c4 * 4 + 2], e4.z, acc);
            acc = fmaf(lz2[c4 * 4 + 3], e4.w, acc);
        }
        const float v = __fadd_rn(__fsub_rn(sa[0], acc), Nf[k]);
        u64t key = ((u64t)__float_as_uint(v) << 32) | (unsigned)k;
#pragma unroll
        for (int m = 1; m <= 32; m <<= 1) {
            const u64t o = __shfl_xor(key, m, 64);
            key = (o < key) ? o : key;
        }
        if ((t & 63) == 0) lw4[t >> 6] = key;
        __syncthreads();
        if (t == 0) {
            u64t bk = lw4[0];
            bk = (lw4[1] < bk) ? lw4[1] : bk;
            bk = (lw4[2] < bk) ? lw4[2] : bk;
            bk = (lw4[3] < bk) ? lw4[3] : bk;
            atomicMin(&amin[px], bk);
        }
    }
}

// ---------------------------------------------------------------- fallback (ws too small): r10 VALU distance kernel
__global__ __launch_bounds__(256) void k_init(u64t* __restrict__ amin) {
    amin[blockIdx.x * 256 + threadIdx.x] = ~0ULL;
}

__global__ __launch_bounds__(256, 2) void k_dist_r10(const float* __restrict__ ze,
                                                     const float* __restrict__ embed,
                                                     const float* __restrict__ A,
                                                     const float* __restrict__ Nf,
                                                     u64t* __restrict__ amin) {
    __shared__ __align__(16) char smem[49152];
    float (*le)[128] = reinterpret_cast<float (*)[128]>(smem);
    float (*z2)[256] = reinterpret_cast<float (*)[256]>(smem + 16384);
    u64t* red = reinterpret_cast<u64t*>(smem);

    const int t    = threadIdx.x;
    const int ks   = blockIdx.x & 31;
    const int pt   = blockIdx.x >> 5;
    const int pix0 = pt * 256;
    const int k0   = ks * 256;
    const int tp   = t & 15, tk = t >> 4;
    const int er   = t >> 1, eh2 = (t & 1) * 16;

    float best[16];
    int   bidx[16];
#pragma unroll
    for (int i = 0; i < 16; ++i) { best[i] = 3.402823466e+38f; bidx[i] = 0x7fffffff; }

    float Ai[16];
#pragma unroll
    for (int q = 0; q < 4; ++q)
#pragma unroll
        for (int m = 0; m < 4; ++m)
            Ai[q * 4 + m] = A[pix0 + (q * 16 + tp) * 4 + m];

    for (int kc = 0; kc < 256; kc += 128) {
        float acc[16][8];
#pragma unroll
        for (int i = 0; i < 16; ++i)
#pragma unroll
            for (int j = 0; j < 8; ++j) acc[i][j] = 0.0f;
        const int kbase = k0 + kc + tk * 8;
        for (int cc = 0; cc < 256; cc += 32) {
            float4 se[4], sz[8];
            const float4* esrc = reinterpret_cast<const float4*>(
                embed + (size_t)(k0 + kc + er) * 256 + cc + eh2);
#pragma unroll
            for (int m = 0; m < 4; ++m) se[m] = esrc[m];
            const float4* zsrc = reinterpret_cast<const float4*>(
                ze + (size_t)(pix0 + t) * 256 + cc);
#pragma unroll
            for (int m = 0; m < 8; ++m) sz[m] = zsrc[m];
            __syncthreads();
#pragma unroll
            for (int m = 0; m < 4; ++m) {
                le[eh2 + m * 4 + 0][er] = se[m].x;
                le[eh2 + m * 4 + 1][er] = se[m].y;
                le[eh2 + m * 4 + 2][er] = se[m].z;
                le[eh2 + m * 4 + 3][er] = se[m].w;
            }
#pragma unroll
            for (int m = 0; m < 8; ++m) {
                z2[m * 4 + 0][t] = __fmul_rn(2.0f, sz[m].x);
                z2[m * 4 + 1][t] = __fmul_rn(2.0f, sz[m].y);
                z2[m * 4 + 2][t] = __fmul_rn(2.0f, sz[m].z);
                z2[m * 4 + 3][t] = __fmul_rn(2.0f, sz[m].w);
            }
            __syncthreads();
#pragma unroll 2
            for (int c = 0; c < 32; ++c) {
                const float4 e0 = *reinterpret_cast<const float4*>(&le[c][tk * 8]);
                const float4 e1 = *reinterpret_cast<const float4*>(&le[c][tk * 8 + 4]);
                float4 zq[4];
#pragma unroll
                for (int q = 0; q < 4; ++q)
                    zq[q] = *reinterpret_cast<const float4*>(&z2[c][(q * 16 + tp) * 4]);
#define FMA8(i, zv)                                          \
    acc[i][0] = fmaf(zv, e0.x, acc[i][0]);                   \
    acc[i][1] = fmaf(zv, e0.y, acc[i][1]);                   \
    acc[i][2] = fmaf(zv, e0.z, acc[i][2]);                   \
    acc[i][3] = fmaf(zv, e0.w, acc[i][3]);                   \
    acc[i][4] = fmaf(zv, e1.x, acc[i][4]);                   \
    acc[i][5] = fmaf(zv, e1.y, acc[i][5]);                   \
    acc[i][6] = fmaf(zv, e1.z, acc[i][6]);                   \
    acc[i][7] = fmaf(zv, e1.w, acc[i][7]);
#pragma unroll
                for (int q = 0; q < 4; ++q) {
                    FMA8(q * 4 + 0, zq[q].x)
                    FMA8(q * 4 + 1, zq[q].y)
                    FMA8(q * 4 + 2, zq[q].z)
                    FMA8(q * 4 + 3, zq[q].w)
                }
#undef FMA8
            }
        }
        const float4 n0 = *reinterpret_cast<const float4*>(&Nf[kbase]);
        const float4 n1 = *reinterpret_cast<const float4*>(&Nf[kbase + 4]);
        const float nk[8] = {n0.x, n0.y, n0.z, n0.w, n1.x, n1.y, n1.z, n1.w};
#pragma unroll
        for (int j = 0; j < 8; ++j) {
            const int k = kbase + j;
#pragma unroll
            for (int i = 0; i < 16; ++i) {
                const float v = __fadd_rn(__fsub_rn(Ai[i], acc[i][j]), nk[j]);
                if (v < best[i]) { best[i] = v; bidx[i] = k; }
            }
        }
    }
    __syncthreads();
#pragma unroll
    for (int i = 0; i < 16; ++i) {
        const int px = ((i >> 2) * 16 + tp) * 4 + (i & 3);
        const unsigned u = __float_as_uint(best[i]);
        red[px * 17 + tk] = ((u64t)u << 32) | (unsigned)bidx[i];
    }
    __syncthreads();
    {
        u64t bvv = ~0ULL;
#pragma unroll 4
        for (int q2 = 0; q2 < 16; ++q2) {
            const u64t v = red[t * 17 + q2];
            bvv = (v < bvv) ? v : bvv;
        }
        atomicMin(&amin[pix0 + t], bvv);
    }
}

// ---------------------------------------------------------------- unpack argmin
__global__ __launch_bounds__(256) void k_combine(const u64t* __restrict__ amin,
                                                 float* __restrict__ out_ind) {
    const int nn = blockIdx.x * 256 + threadIdx.x;
    out_ind[nn] = (float)(unsigned)(amin[nn] & 0xffffffffULL);
}

// ---------------------------------------------------------------- gather z_q (overwrite z_e) + partial MSE (f64)
__global__ __launch_bounds__(256) void k_gather(const float* __restrict__ embed,
                                                float* __restrict__ out,
                                                const float* __restrict__ out_ind,
                                                float* __restrict__ part) {
    __shared__ double wsum[4];
    const int t = threadIdx.x;
    const int g = t >> 5, ll = t & 31;
    const int nn = blockIdx.x * 8 + g;
    const int idx = (int)(out_ind[nn] + 0.5f);
    const float4* ev4 = reinterpret_cast<const float4*>(embed + (size_t)idx * 256);
    float4* zp = reinterpret_cast<float4*>(out + (size_t)nn * 256);
    double sm = 0.0;
#pragma unroll
    for (int r = 0; r < 2; ++r) {
        const float4 ev = ev4[ll + r * 32];
        const float4 zv = zp[ll + r * 32];
        const double dx = (double)ev.x - zv.x, dy = (double)ev.y - zv.y;
        const double dz = (double)ev.z - zv.z, dw = (double)ev.w - zv.w;
        sm += dx * dx + dy * dy + dz * dz + dw * dw;
        zp[ll + r * 32] = ev;
    }
    for (int off = 32; off; off >>= 1) sm += __shfl_down(sm, off, 64);
    const int wid = t >> 6, lane = t & 63;
    if (lane == 0) wsum[wid] = sm;
    __syncthreads();
    if (t == 0) part[blockIdx.x] = (float)(wsum[0] + wsum[1] + wsum[2] + wsum[3]);
}

// ---------------------------------------------------------------- final diff reduction (f64)
__global__ __launch_bounds__(256) void k_final(const float* __restrict__ part,
                                               float* __restrict__ out_diff) {
    __shared__ double wsum[4];
    double sm = 0.0;
#pragma unroll
    for (int i = 0; i < 4; ++i) sm += (double)part[threadIdx.x + i * 256];
    for (int off = 32; off; off >>= 1) sm += __shfl_down(sm, off, 64);
    const int wid = threadIdx.x >> 6, lane = threadIdx.x & 63;
    if (lane == 0) wsum[wid] = sm;
    __syncthreads();
    if (threadIdx.x == 0)
        out_diff[0] = (float)(2.0 * (wsum[0] + wsum[1] + wsum[2] + wsum[3]) / 2097152.0);
}

extern "C" void kernel_launch(void* const* d_in, const int* in_sizes, int n_in,
                              void* d_out, int out_size, void* d_ws, size_t ws_size,
                              hipStream_t stream) {
    const float* z     = (const float*)d_in[0];
    const float* pw    = (const float*)d_in[1];
    const float* pb    = (const float*)d_in[2];
    const float* embed = (const float*)d_in[3];
    float* out = (float*)d_out;
    char*  ws  = (char*)d_ws;

    u64t*  amin = (u64t*)(ws + WS_AMIN);
    float* A    = (float*)(ws + WS_A);
    float* Nf   = (float*)(ws + WS_N);
    float* thr  = (float*)(ws + WS_THR);
    float* part = (float*)(ws + WS_PART);

    float* ze       = out + OUT_ZQ;      // z_e lives in z_q slot, overwritten by gather
    float* out_diff = out + OUT_DIFF;
    float* out_ind  = out + OUT_IND;

    const bool big = (ws_size >= WS_BIG_END);

    k_ze_np   <<<512,  256, 0, stream>>>(z, pw, pb, ze);
    k_rowstats<<<64,   256, 0, stream>>>(ze, embed, A, Nf);
    if (big) {
        float*          bv1 = (float*)(ws + WS_BV1);
        unsigned short* bi1 = (unsigned short*)(ws + WS_BI1);
        float*          bv2 = (float*)(ws + WS_BV2);
        unsigned short* bi2 = (unsigned short*)(ws + WS_BI2);
        float*          b3v = (float*)(ws + WS_B3V);
        unsigned short* zh3 = (unsigned short*)(ws + WS_ZH3);
        unsigned short* zl3 = (unsigned short*)(ws + WS_ZL3);
        unsigned short* eh3 = (unsigned short*)(ws + WS_EH3);
        unsigned short* el3 = (unsigned short*)(ws + WS_EL3);
        k_cvt   <<<2048, 256, 0, stream>>>(ze, embed, zh3, zl3, eh3, el3);
        k_mfma  <<<1024, 256, 0, stream>>>(A, Nf, zh3, zl3, eh3, el3, bv1, bi1, bv2, bi2, b3v);
        k_selres<<<32,   256, 0, stream>>>(ze, embed, A, Nf, bv1, bi1, bv2, bi2, thr, amin);
        k_deep  <<<2048, 256, 0, stream>>>(ze, embed, A, Nf, thr, b3v, amin);
    } else {
        k_init    <<<32,   256, 0, stream>>>(amin);
        k_dist_r10<<<1024, 256, 0, stream>>>(ze, embed, A, Nf, amin);
    }
    k_combine <<<32,   256, 0, stream>>>(amin, out_ind);
    k_gather  <<<1024, 256, 0, stream>>>(embed, out + OUT_ZQ, out_ind, part);
    k_final   <<<1,    256, 0, stream>>>(part, out_diff);
}

// Round 19
// 232.002 us; speedup vs baseline: 1.4003x; 1.4003x over previous
//
#include <hip/hip_runtime.h>

#define OUT_ZQ   0
#define OUT_DIFF 2097152
#define OUT_IND  2097153

// ws layout (bytes) — big path total 18,087,936
#define WS_AMIN   0        // u64[8192]
#define WS_A      65536    // f32[8192]
#define WS_N      98304    // f32[8192]
#define WS_EMAX   131072   // u32
#define WS_DLIST  131136   // u16[4][8192] = 64 KB
#define WS_DCNT   196672   // i32[4]
#define WS_PART   196688   // f32[1024]
#define WS_CCNT   200784   // i32 (+pad)
#define WS_CND    200848   // u32[98304]
#define WS_BQ     594064   // u64[4][2][8192] = 512 KB  (top-2 keys per split)
#define WS_B3V    1118352  // f32[4][8192]              (3rd-best VALUE per split)
#define WS_ZH3    1310720  // u16[2M] = 4 MB  fragment-major hi(2*z_e)
#define WS_ZL3    5505024  // lo(2*z_e)
#define WS_EH3    9699328  // hi(embed)
#define WS_EL3    13893632 // lo(embed)
#define WS_BIG_END 18087936ULL
#define CAND_CAP  98304

typedef unsigned long long u64t;
typedef __attribute__((ext_vector_type(8))) short bf16x8;
typedef __attribute__((ext_vector_type(4))) float f32x4;

__device__ inline unsigned short bf16rn(float f) {
    unsigned u = __float_as_uint(f);
    return (unsigned short)((u + 0x7fffu + ((u >> 16) & 1u)) >> 16);
}
__device__ inline float bf16tof(unsigned short h) { return __uint_as_float(((unsigned)h) << 16); }
__device__ inline float valf(u64t k) { return __uint_as_float((unsigned)(k >> 32)); }

#define INITKEY ((((u64t)0x7F7FFFFFu) << 32) | 0xFFFFu)   // value = FLT_MAX (no NaN)

// ---------------------------------------------------------------- init
__global__ __launch_bounds__(256) void k_init(u64t* __restrict__ amin,
                                              int* __restrict__ dcnt,
                                              unsigned* __restrict__ e2) {
    const int i = blockIdx.x * 256 + threadIdx.x;
    amin[i] = ~0ULL;
    if (i < 4) dcnt[i] = 0;
    if (i == 4) *e2 = 0u;
}

// ---------------------------------------------------------------- z_e: bit-exact np.einsum replica (v2: weights in regs, b128 broadcast lz)
__global__ __launch_bounds__(256) void k_ze_np(const float* __restrict__ z,
                                               const float* __restrict__ pw,
                                               const float* __restrict__ pb,
                                               float* __restrict__ ze) {
    __shared__ float lz[32][16];
    const int t   = threadIdx.x;
    const int b   = blockIdx.x >> 6;
    const int hw0 = (blockIdx.x & 63) * 16;

    float acc[16];
#pragma unroll
    for (int p = 0; p < 16; ++p) acc[p] = 0.0f;

    for (int cc = 0; cc < 256; cc += 32) {
        float4 wv[8];
        const float4* wsrc = reinterpret_cast<const float4*>(pw + (size_t)t * 256 + cc);
#pragma unroll
        for (int i = 0; i < 8; ++i) wv[i] = wsrc[i];
        float zv[2];
#pragma unroll
        for (int i = 0; i < 2; ++i) {
            const int f = t + i * 256;
            zv[i] = z[(size_t)(b * 256 + cc + (f >> 4)) * 1024 + hw0 + (f & 15)];
        }
        __syncthreads();
#pragma unroll
        for (int i = 0; i < 2; ++i) {
            const int f = t + i * 256;
            lz[f >> 4][f & 15] = zv[i];
        }
        __syncthreads();
#define ZSTEP(CL, WL) {                                                     \
    const float4 q0 = *reinterpret_cast<const float4*>(&lz[CL][0]);         \
    const float4 q1 = *reinterpret_cast<const float4*>(&lz[CL][4]);         \
    const float4 q2 = *reinterpret_cast<const float4*>(&lz[CL][8]);         \
    const float4 q3 = *reinterpret_cast<const float4*>(&lz[CL][12]);        \
    acc[0]  = __fadd_rn(acc[0],  __fmul_rn(q0.x, WL));                      \
    acc[1]  = __fadd_rn(acc[1],  __fmul_rn(q0.y, WL));                      \
    acc[2]  = __fadd_rn(acc[2],  __fmul_rn(q0.z, WL));                      \
    acc[3]  = __fadd_rn(acc[3],  __fmul_rn(q0.w, WL));                      \
    acc[4]  = __fadd_rn(acc[4],  __fmul_rn(q1.x, WL));                      \
    acc[5]  = __fadd_rn(acc[5],  __fmul_rn(q1.y, WL));                      \
    acc[6]  = __fadd_rn(acc[6],  __fmul_rn(q1.z, WL));                      \
    acc[7]  = __fadd_rn(acc[7],  __fmul_rn(q1.w, WL));                      \
    acc[8]  = __fadd_rn(acc[8],  __fmul_rn(q2.x, WL));                      \
    acc[9]  = __fadd_rn(acc[9],  __fmul_rn(q2.y, WL));                      \
    acc[10] = __fadd_rn(acc[10], __fmul_rn(q2.z, WL));                      \
    acc[11] = __fadd_rn(acc[11], __fmul_rn(q2.w, WL));                      \
    acc[12] = __fadd_rn(acc[12], __fmul_rn(q3.x, WL));                      \
    acc[13] = __fadd_rn(acc[13], __fmul_rn(q3.y, WL));                      \
    acc[14] = __fadd_rn(acc[14], __fmul_rn(q3.z, WL));                      \
    acc[15] = __fadd_rn(acc[15], __fmul_rn(q3.w, WL)); }
#pragma unroll
        for (int c8 = 0; c8 < 8; ++c8) {
            const float4 wq = wv[c8];
            ZSTEP(c8 * 4 + 0, wq.x)
            ZSTEP(c8 * 4 + 1, wq.y)
            ZSTEP(c8 * 4 + 2, wq.z)
            ZSTEP(c8 * 4 + 3, wq.w)
        }
#undef ZSTEP
    }
    const float bb = pb[t];
#pragma unroll
    for (int p = 0; p < 16; ++p)
        ze[(size_t)(b * 1024 + hw0 + p) * 256 + t] = __fadd_rn(acc[p], bb);
}

// ---------------------------------------------------------------- np pairwise row-norms
__global__ __launch_bounds__(256) void k_rowstats(const float* __restrict__ ze,
                                                  const float* __restrict__ embed,
                                                  float* __restrict__ A,
                                                  float* __restrict__ Nf,
                                                  unsigned* __restrict__ e2) {
    const int gid = blockIdx.x * 256 + threadIdx.x;
    const float* row = (gid < 8192) ? (ze + (size_t)gid * 256)
                                    : (embed + (size_t)(gid - 8192) * 256);
    float blk[2];
#pragma unroll
    for (int half = 0; half < 2; ++half) {
        const float4* r4 = reinterpret_cast<const float4*>(row + half * 128);
        float r[8];
#pragma unroll
        for (int i = 0; i < 16; ++i) {
            const float4 a = r4[i * 2], b = r4[i * 2 + 1];
            const float s[8] = {__fmul_rn(a.x, a.x), __fmul_rn(a.y, a.y),
                                __fmul_rn(a.z, a.z), __fmul_rn(a.w, a.w),
                                __fmul_rn(b.x, b.x), __fmul_rn(b.y, b.y),
                                __fmul_rn(b.z, b.z), __fmul_rn(b.w, b.w)};
            if (i == 0) {
#pragma unroll
                for (int j = 0; j < 8; ++j) r[j] = s[j];
            } else {
#pragma unroll
                for (int j = 0; j < 8; ++j) r[j] = __fadd_rn(r[j], s[j]);
            }
        }
        blk[half] = __fadd_rn(__fadd_rn(__fadd_rn(r[0], r[1]), __fadd_rn(r[2], r[3])),
                              __fadd_rn(__fadd_rn(r[4], r[5]), __fadd_rn(r[6], r[7])));
    }
    const float res = __fadd_rn(blk[0], blk[1]);
    if (gid < 8192) A[gid] = res;
    else {
        Nf[gid - 8192] = res;
        float mx = res;
        for (int off = 32; off; off >>= 1) mx = fmaxf(mx, __shfl_down(mx, off, 64));
        if ((threadIdx.x & 63) == 0) atomicMax(e2, __float_as_uint(mx));
    }
}

// ---------------------------------------------------------------- bf16 hi/lo precompute in FRAGMENT-MAJOR layout
// z elem (px,c): pt=px>>6 ti=(px>>4)&3 lr=px&15; ci=c>>5 lg=(c>>3)&3; lane=lg*16+lr
//   zh3 idx = ((ci*128+pt)*4+ti)*512 + lane*8 + (c&7)
// e elem (k,c):  ks=k>>11 ksub=(k>>8)&7 w=(k>>6)&3 tj=(k>>4)&3 lr=k&15
//   eh3 idx = (((ks*8+ksub)*8+ci)*16 + w*4 + tj)*512 + lane*8 + (c&7)
__global__ __launch_bounds__(256) void k_cvt(const float* __restrict__ ze,
                                             const float* __restrict__ embed,
                                             unsigned short* __restrict__ zh3,
                                             unsigned short* __restrict__ zl3,
                                             unsigned short* __restrict__ eh3,
                                             unsigned short* __restrict__ el3,
                                             int* __restrict__ ccnt) {
    const int gid = blockIdx.x * 256 + threadIdx.x;
    if (gid == 0) *ccnt = 0;
    const int row = gid >> 5;
    const int c0  = (gid & 31) * 8;
    const bool isz = (row < 8192);
    const float* src = (isz ? ze + (size_t)row * 256 : embed + (size_t)(row - 8192) * 256) + c0;
    const float4 v0 = reinterpret_cast<const float4*>(src)[0];
    const float4 v1 = reinterpret_cast<const float4*>(src)[1];
    float x[8] = {v0.x, v0.y, v0.z, v0.w, v1.x, v1.y, v1.z, v1.w};
    if (isz) {
#pragma unroll
        for (int i = 0; i < 8; ++i) x[i] = __fmul_rn(2.0f, x[i]);   // exact prescale
    }
    unsigned short hv[8], lv[8];
#pragma unroll
    for (int i = 0; i < 8; ++i) {
        hv[i] = bf16rn(x[i]);
        lv[i] = bf16rn(__fsub_rn(x[i], bf16tof(hv[i])));
    }
    const int ci = c0 >> 5, lg = (c0 >> 3) & 3;
    if (isz) {
        const int pt = row >> 6, ti = (row >> 4) & 3, lr = row & 15;
        const int lane = lg * 16 + lr;
        const size_t off = ((size_t)(ci * 128 + pt) * 4 + ti) * 512 + (size_t)lane * 8;
        *reinterpret_cast<ushort4*>(zh3 + off)     = make_ushort4(hv[0], hv[1], hv[2], hv[3]);
        *reinterpret_cast<ushort4*>(zh3 + off + 4) = make_ushort4(hv[4], hv[5], hv[6], hv[7]);
        *reinterpret_cast<ushort4*>(zl3 + off)     = make_ushort4(lv[0], lv[1], lv[2], lv[3]);
        *reinterpret_cast<ushort4*>(zl3 + off + 4) = make_ushort4(lv[4], lv[5], lv[6], lv[7]);
    } else {
        const int k = row - 8192;
        const int ks = k >> 11, ksub = (k >> 8) & 7, w = (k >> 6) & 3, tj = (k >> 4) & 3, lr = k & 15;
        const int lane = lg * 16 + lr;
        const size_t off = (((size_t)((ks * 8 + ksub) * 8 + ci) * 16) + w * 4 + tj) * 512 + (size_t)lane * 8;
        *reinterpret_cast<ushort4*>(eh3 + off)     = make_ushort4(hv[0], hv[1], hv[2], hv[3]);
        *reinterpret_cast<ushort4*>(eh3 + off + 4) = make_ushort4(hv[4], hv[5], hv[6], hv[7]);
        *reinterpret_cast<ushort4*>(el3 + off)     = make_ushort4(lv[0], lv[1], lv[2], lv[3]);
        *reinterpret_cast<ushort4*>(el3 + off + 4) = make_ushort4(lv[4], lv[5], lv[6], lv[7]);
    }
}

// ---------------------------------------------------------------- MFMA screen v3: no LDS/barriers in main loop (r15/16-proven)
__global__ __launch_bounds__(256, 2) void k_mfma(const float* __restrict__ A,
                                                 const float* __restrict__ Nf,
                                                 const unsigned short* __restrict__ zh3,
                                                 const unsigned short* __restrict__ zl3,
                                                 const unsigned short* __restrict__ eh3,
                                                 const unsigned short* __restrict__ el3,
                                                 u64t* __restrict__ bq12,
                                                 float* __restrict__ b3v) {
    __shared__ u64t  mrgk[64][4][2];
    __shared__ float mrgv[64][4];
    const int t = threadIdx.x;
    const int ks = blockIdx.x & 3, pt = blockIdx.x >> 2;
    const int pix0 = pt * 64;
    const int w = t >> 6, l = t & 63;
    const int lg = l >> 4, lr = l & 15;

    float a_reg[4][4];
#pragma unroll
    for (int ti = 0; ti < 4; ++ti)
#pragma unroll
        for (int r = 0; r < 4; ++r)
            a_reg[ti][r] = A[pix0 + ti * 16 + lg * 4 + r];

    u64t b1[4][4], b2[4][4];
    float bv[4][4];
#pragma unroll
    for (int ti = 0; ti < 4; ++ti)
#pragma unroll
        for (int r = 0; r < 4; ++r) { b1[ti][r] = INITKEY; b2[ti][r] = INITKEY; bv[ti][r] = 3.402823466e+38f; }

    const size_t zoff0 = (size_t)pt * 2048 + (size_t)l * 8;
    for (int ksub = 0; ksub < 8; ++ksub) {
        f32x4 acc[4][4];
#pragma unroll
        for (int ti = 0; ti < 4; ++ti)
#pragma unroll
            for (int tj = 0; tj < 4; ++tj) acc[ti][tj] = (f32x4)(0.0f);

        const size_t ebase = (size_t)(ks * 8 + ksub) * 65536 + (size_t)w * 2048 + (size_t)l * 8;
#pragma unroll 2
        for (int ci = 0; ci < 8; ++ci) {
            const size_t zo = zoff0 + (size_t)ci * 262144;
            const size_t eo = ebase + (size_t)ci * 8192;
            bf16x8 az[4], alz[4], be[4], ble[4];
#pragma unroll
            for (int ti = 0; ti < 4; ++ti) {
                az[ti]  = *reinterpret_cast<const bf16x8*>(zh3 + zo + (size_t)ti * 512);
                alz[ti] = *reinterpret_cast<const bf16x8*>(zl3 + zo + (size_t)ti * 512);
            }
#pragma unroll
            for (int tj = 0; tj < 4; ++tj) {
                be[tj]  = *reinterpret_cast<const bf16x8*>(eh3 + eo + (size_t)tj * 512);
                ble[tj] = *reinterpret_cast<const bf16x8*>(el3 + eo + (size_t)tj * 512);
            }
#pragma unroll
            for (int tj = 0; tj < 4; ++tj)
#pragma unroll
                for (int ti = 0; ti < 4; ++ti) {
                    acc[ti][tj] = __builtin_amdgcn_mfma_f32_16x16x32_bf16(az[ti],  be[tj],  acc[ti][tj], 0, 0, 0);
                    acc[ti][tj] = __builtin_amdgcn_mfma_f32_16x16x32_bf16(az[ti],  ble[tj], acc[ti][tj], 0, 0, 0);
                    acc[ti][tj] = __builtin_amdgcn_mfma_f32_16x16x32_bf16(alz[ti], be[tj],  acc[ti][tj], 0, 0, 0);
                }
        }
#pragma unroll
        for (int tj = 0; tj < 4; ++tj) {
            const int kk = ks * 2048 + ksub * 256 + w * 64 + tj * 16 + lr;
            const float nk = Nf[kk];
#pragma unroll
            for (int ti = 0; ti < 4; ++ti)
#pragma unroll
                for (int r = 0; r < 4; ++r) {
                    const float vv = __fadd_rn(__fsub_rn(a_reg[ti][r], acc[ti][tj][r]), nk);
                    const u64t key = ((u64t)__float_as_uint(vv) << 32) | (unsigned)kk;
                    if (key < b2[ti][r]) {
                        bv[ti][r] = valf(b2[ti][r]);
                        if (key < b1[ti][r]) { b2[ti][r] = b1[ti][r]; b1[ti][r] = key; }
                        else                 { b2[ti][r] = key; }
                    } else {
                        bv[ti][r] = fminf(bv[ti][r], vv);
                    }
                }
        }
    }
#pragma unroll
    for (int ti = 0; ti < 4; ++ti)
#pragma unroll
        for (int r = 0; r < 4; ++r) {
            u64t k1 = b1[ti][r], k2 = b2[ti][r];
            float v3 = bv[ti][r];
#pragma unroll
            for (int m = 1; m <= 8; m <<= 1) {
                const u64t o1 = __shfl_xor(k1, m, 64);
                const u64t o2 = __shfl_xor(k2, m, 64);
                const float ov = __shfl_xor(v3, m, 64);
                const u64t n1 = (k1 < o1) ? k1 : o1;
                const u64t X  = (k1 < o1) ? o1 : k1;
                const u64t Y  = (k2 < o2) ? k2 : o2;
                const u64t n2 = (X < Y) ? X : Y;
                const u64t t4 = (X < Y) ? Y : X;
                v3 = fminf(fminf(v3, ov), valf(t4));
                k1 = n1; k2 = n2;
            }
            b1[ti][r] = k1; b2[ti][r] = k2; bv[ti][r] = v3;
        }
    if (lr == 0) {
#pragma unroll
        for (int ti = 0; ti < 4; ++ti)
#pragma unroll
            for (int r = 0; r < 4; ++r) {
                const int pxl = ti * 16 + lg * 4 + r;
                mrgk[pxl][w][0] = b1[ti][r];
                mrgk[pxl][w][1] = b2[ti][r];
                mrgv[pxl][w]    = bv[ti][r];
            }
    }
    __syncthreads();
    if (t < 64) {
        u64t K1 = INITKEY, K2 = INITKEY;
        float V3 = 3.402823466e+38f;
#pragma unroll
        for (int w4 = 0; w4 < 4; ++w4) {
            const u64t o1 = mrgk[t][w4][0], o2 = mrgk[t][w4][1];
            const float ov = mrgv[t][w4];
            const u64t n1 = (K1 < o1) ? K1 : o1;
            const u64t X  = (K1 < o1) ? o1 : K1;
            const u64t Y  = (K2 < o2) ? K2 : o2;
            const u64t n2 = (X < Y) ? X : Y;
            const u64t t4 = (X < Y) ? Y : X;
            V3 = fminf(fminf(V3, ov), valf(t4));
            K1 = n1; K2 = n2;
        }
        bq12[((size_t)(ks * 2 + 0)) * 8192 + pix0 + t] = K1;
        bq12[((size_t)(ks * 2 + 1)) * 8192 + pix0 + t] = K2;
        b3v[(size_t)ks * 8192 + pix0 + t] = V3;
    }
}

// ---------------------------------------------------------------- select: candidates + deep flags (3rd-VALUE gated)
__global__ __launch_bounds__(256) void k_sel(const float* __restrict__ A,
                                             const u64t* __restrict__ bq12,
                                             const float* __restrict__ b3v,
                                             unsigned short* __restrict__ dlist,
                                             int* __restrict__ dcnt,
                                             int* __restrict__ ccnt,
                                             unsigned* __restrict__ cnd) {
    const int px = blockIdx.x * 256 + threadIdx.x;
    const int lane = threadIdx.x & 63;
    u64t k1[4], k2[4];
    float v3[4];
#pragma unroll
    for (int s = 0; s < 4; ++s) {
        k1[s] = bq12[((size_t)(s * 2 + 0)) * 8192 + px];
        k2[s] = bq12[((size_t)(s * 2 + 1)) * 8192 + px];
        v3[s] = b3v[(size_t)s * 8192 + px];
    }
    float m = valf(k1[0]);
#pragma unroll
    for (int s = 1; s < 4; ++s) m = fminf(m, valf(k1[s]));
    const float a = A[px];
    const unsigned eb = (__float_as_uint(a + 0.125f) >> 23) & 255u;
    const float up = __uint_as_float((eb - 23u) << 23);
    const float thresh = m + 4.5f * up + 1.0e-5f;

    unsigned cand[8];
    int nc = 0;
#pragma unroll
    for (int s = 0; s < 4; ++s) {
        if (valf(k1[s]) <= thresh) cand[nc++] = ((unsigned)px << 16) | (unsigned)(k1[s] & 0xffffu);
        if (valf(k2[s]) <= thresh) cand[nc++] = ((unsigned)px << 16) | (unsigned)(k2[s] & 0xffffu);
        if (v3[s] <= thresh) {
            const int pos = atomicAdd(&dcnt[s], 1);
            if (pos < 8192) dlist[s * 8192 + pos] = (unsigned short)px;
        }
    }
    int sc = nc;
#pragma unroll
    for (int o = 1; o < 64; o <<= 1) {
        const int n = __shfl_up(sc, o, 64);
        if (lane >= o) sc += n;
    }
    int base = 0;
    if (lane == 63) base = atomicAdd(ccnt, sc);
    base = __shfl(base, 63, 64);
    const int off = base + sc - nc;
    for (int j = 0; j < nc; ++j)
        if (off + j < CAND_CAP) cnd[off + j] = cand[j];
}

// ---------------------------------------------------------------- candidate np-exact rescore
__global__ __launch_bounds__(256) void k_cand(const float* __restrict__ ze,
                                              const float* __restrict__ embed,
                                              const float* __restrict__ A,
                                              const float* __restrict__ Nf,
                                              const int* __restrict__ ccnt,
                                              const unsigned* __restrict__ cnd,
                                              u64t* __restrict__ amin) {
    int cnt = *ccnt; if (cnt > CAND_CAP) cnt = CAND_CAP;
    for (int i = blockIdx.x * 256 + threadIdx.x; i < cnt; i += 32768) {
        const unsigned pk = cnd[i];
        const int px = pk >> 16, k = pk & 0xffffu;
        const float4* zr = reinterpret_cast<const float4*>(ze + (size_t)px * 256);
        const float4* er = reinterpret_cast<const float4*>(embed + (size_t)k * 256);
        float acc = 0.0f;
        for (int c4 = 0; c4 < 64; ++c4) {
            const float4 z4 = zr[c4], e4 = er[c4];
            acc = fmaf(__fmul_rn(2.0f, z4.x), e4.x, acc);
            acc = fmaf(__fmul_rn(2.0f, z4.y), e4.y, acc);
            acc = fmaf(__fmul_rn(2.0f, z4.z), e4.z, acc);
            acc = fmaf(__fmul_rn(2.0f, z4.w), e4.w, acc);
        }
        const float v = __fadd_rn(__fsub_rn(A[px], acc), Nf[k]);
        atomicMin(&amin[px], ((u64t)__float_as_uint(v) << 32) | (unsigned)k);
    }
}

// ---------------------------------------------------------------- deep v3: one block per (flagged px, 256-k slice)
__global__ __launch_bounds__(256) void k_deep(const float* __restrict__ ze,
                                              const float* __restrict__ embed,
                                              const float* __restrict__ A,
                                              const float* __restrict__ Nf,
                                              const unsigned short* __restrict__ dlist,
                                              const int* __restrict__ dcnt,
                                              u64t* __restrict__ amin) {
    __shared__ float lz2[256];
    __shared__ float sa[1];
    __shared__ u64t lw4[4];
    const int t = threadIdx.x;
    int n0 = dcnt[0], n1 = dcnt[1], n2 = dcnt[2], n3 = dcnt[3];
    n0 = (n0 > 8192) ? 8192 : n0;  n1 = (n1 > 8192) ? 8192 : n1;
    n2 = (n2 > 8192) ? 8192 : n2;  n3 = (n3 > 8192) ? 8192 : n3;
    const int tot = (n0 + n1 + n2 + n3) * 8;

    for (int it = blockIdx.x; it < tot; it += gridDim.x) {
        const int q = it >> 3, slice = it & 7;
        int s, pxi;
        if (q < n0)                { s = 0; pxi = q; }
        else if (q < n0 + n1)      { s = 1; pxi = q - n0; }
        else if (q < n0 + n1 + n2) { s = 2; pxi = q - n0 - n1; }
        else                       { s = 3; pxi = q - n0 - n1 - n2; }
        const int px = dlist[s * 8192 + pxi];

        __syncthreads();   // protect lz2/lw4 from previous iteration's readers
        lz2[t] = __fmul_rn(2.0f, ze[(size_t)px * 256 + t]);   // exact prescale
        if (t == 0) sa[0] = A[px];
        __syncthreads();

        const int k = s * 2048 + slice * 256 + t;
        const float4* er = reinterpret_cast<const float4*>(embed + (size_t)k * 256);
        float acc = 0.0f;
#pragma unroll 8
        for (int c4 = 0; c4 < 64; ++c4) {
            const float4 e4 = er[c4];
            acc = fmaf(lz2[c4 * 4 + 0], e4.x, acc);
            acc = fmaf(lz2[c4 * 4 + 1], e4.y, acc);
            acc = fmaf(lz2[c4 * 4 + 2], e4.z, acc);
            acc = fmaf(lz2[c4 * 4 + 3], e4.w, acc);
        }
        const float v = __fadd_rn(__fsub_rn(sa[0], acc), Nf[k]);
        u64t key = ((u64t)__float_as_uint(v) << 32) | (unsigned)k;
#pragma unroll
        for (int m = 1; m <= 32; m <<= 1) {
            const u64t o = __shfl_xor(key, m, 64);
            key = (o < key) ? o : key;
        }
        if ((t & 63) == 0) lw4[t >> 6] = key;
        __syncthreads();
        if (t == 0) {
            u64t bk = lw4[0];
            bk = (lw4[1] < bk) ? lw4[1] : bk;
            bk = (lw4[2] < bk) ? lw4[2] : bk;
            bk = (lw4[3] < bk) ? lw4[3] : bk;
            atomicMin(&amin[px], bk);
        }
    }
}

// ---------------------------------------------------------------- fallback (ws too small): r10 VALU distance kernel
__global__ __launch_bounds__(256, 2) void k_dist_r10(const float* __restrict__ ze,
                                                     const float* __restrict__ embed,
                                                     const float* __restrict__ A,
                                                     const float* __restrict__ Nf,
                                                     u64t* __restrict__ amin) {
    __shared__ __align__(16) char smem[49152];
    float (*le)[128] = reinterpret_cast<float (*)[128]>(smem);
    float (*z2)[256] = reinterpret_cast<float (*)[256]>(smem + 16384);
    u64t* red = reinterpret_cast<u64t*>(smem);

    const int t    = threadIdx.x;
    const int ks   = blockIdx.x & 31;
    const int pt   = blockIdx.x >> 5;
    const int pix0 = pt * 256;
    const int k0   = ks * 256;
    const int tp   = t & 15, tk = t >> 4;
    const int er   = t >> 1, eh2 = (t & 1) * 16;

    float best[16];
    int   bidx[16];
#pragma unroll
    for (int i = 0; i < 16; ++i) { best[i] = 3.402823466e+38f; bidx[i] = 0x7fffffff; }

    float Ai[16];
#pragma unroll
    for (int q = 0; q < 4; ++q)
#pragma unroll
        for (int m = 0; m < 4; ++m)
            Ai[q * 4 + m] = A[pix0 + (q * 16 + tp) * 4 + m];

    for (int kc = 0; kc < 256; kc += 128) {
        float acc[16][8];
#pragma unroll
        for (int i = 0; i < 16; ++i)
#pragma unroll
            for (int j = 0; j < 8; ++j) acc[i][j] = 0.0f;
        const int kbase = k0 + kc + tk * 8;
        for (int cc = 0; cc < 256; cc += 32) {
            float4 se[4], sz[8];
            const float4* esrc = reinterpret_cast<const float4*>(
                embed + (size_t)(k0 + kc + er) * 256 + cc + eh2);
#pragma unroll
            for (int m = 0; m < 4; ++m) se[m] = esrc[m];
            const float4* zsrc = reinterpret_cast<const float4*>(
                ze + (size_t)(pix0 + t) * 256 + cc);
#pragma unroll
            for (int m = 0; m < 8; ++m) sz[m] = zsrc[m];
            __syncthreads();
#pragma unroll
            for (int m = 0; m < 4; ++m) {
                le[eh2 + m * 4 + 0][er] = se[m].x;
                le[eh2 + m * 4 + 1][er] = se[m].y;
                le[eh2 + m * 4 + 2][er] = se[m].z;
                le[eh2 + m * 4 + 3][er] = se[m].w;
            }
#pragma unroll
            for (int m = 0; m < 8; ++m) {
                z2[m * 4 + 0][t] = __fmul_rn(2.0f, sz[m].x);
                z2[m * 4 + 1][t] = __fmul_rn(2.0f, sz[m].y);
                z2[m * 4 + 2][t] = __fmul_rn(2.0f, sz[m].z);
                z2[m * 4 + 3][t] = __fmul_rn(2.0f, sz[m].w);
            }
            __syncthreads();
#pragma unroll 2
            for (int c = 0; c < 32; ++c) {
                const float4 e0 = *reinterpret_cast<const float4*>(&le[c][tk * 8]);
                const float4 e1 = *reinterpret_cast<const float4*>(&le[c][tk * 8 + 4]);
                float4 zq[4];
#pragma unroll
                for (int q = 0; q < 4; ++q)
                    zq[q] = *reinterpret_cast<const float4*>(&z2[c][(q * 16 + tp) * 4]);
#define FMA8(i, zv)                                          \
    acc[i][0] = fmaf(zv, e0.x, acc[i][0]);                   \
    acc[i][1] = fmaf(zv, e0.y, acc[i][1]);                   \
    acc[i][2] = fmaf(zv, e0.z, acc[i][2]);                   \
    acc[i][3] = fmaf(zv, e0.w, acc[i][3]);                   \
    acc[i][4] = fmaf(zv, e1.x, acc[i][4]);                   \
    acc[i][5] = fmaf(zv, e1.y, acc[i][5]);                   \
    acc[i][6] = fmaf(zv, e1.z, acc[i][6]);                   \
    acc[i][7] = fmaf(zv, e1.w, acc[i][7]);
#pragma unroll
                for (int q = 0; q < 4; ++q) {
                    FMA8(q * 4 + 0, zq[q].x)
                    FMA8(q * 4 + 1, zq[q].y)
                    FMA8(q * 4 + 2, zq[q].z)
                    FMA8(q * 4 + 3, zq[q].w)
                }
#undef FMA8
            }
        }
        const float4 n0 = *reinterpret_cast<const float4*>(&Nf[kbase]);
        const float4 n1 = *reinterpret_cast<const float4*>(&Nf[kbase + 4]);
        const float nk[8] = {n0.x, n0.y, n0.z, n0.w, n1.x, n1.y, n1.z, n1.w};
#pragma unroll
        for (int j = 0; j < 8; ++j) {
            const int k = kbase + j;
#pragma unroll
            for (int i = 0; i < 16; ++i) {
                const float v = __fadd_rn(__fsub_rn(Ai[i], acc[i][j]), nk[j]);
                if (v < best[i]) { best[i] = v; bidx[i] = k; }
            }
        }
    }
    __syncthreads();
#pragma unroll
    for (int i = 0; i < 16; ++i) {
        const int px = ((i >> 2) * 16 + tp) * 4 + (i & 3);
        const unsigned u = __float_as_uint(best[i]);
        red[px * 17 + tk] = ((u64t)u << 32) | (unsigned)bidx[i];
    }
    __syncthreads();
    {
        u64t bvv = ~0ULL;
#pragma unroll 4
        for (int q2 = 0; q2 < 16; ++q2) {
            const u64t v = red[t * 17 + q2];
            bvv = (v < bvv) ? v : bvv;
        }
        atomicMin(&amin[pix0 + t], bvv);
    }
}

// ---------------------------------------------------------------- unpack argmin
__global__ __launch_bounds__(256) void k_combine(const u64t* __restrict__ amin,
                                                 float* __restrict__ out_ind) {
    const int nn = blockIdx.x * 256 + threadIdx.x;
    out_ind[nn] = (float)(unsigned)(amin[nn] & 0xffffffffULL);
}

// ---------------------------------------------------------------- gather z_q (overwrite z_e) + partial MSE (f64)
__global__ __launch_bounds__(256) void k_gather(const float* __restrict__ embed,
                                                float* __restrict__ out,
                                                const float* __restrict__ out_ind,
                                                float* __restrict__ part) {
    __shared__ double wsum[4];
    const int t = threadIdx.x;
    const int g = t >> 5, ll = t & 31;
    const int nn = blockIdx.x * 8 + g;
    const int idx = (int)(out_ind[nn] + 0.5f);
    const float4* ev4 = reinterpret_cast<const float4*>(embed + (size_t)idx * 256);
    float4* zp = reinterpret_cast<float4*>(out + (size_t)nn * 256);
    double sm = 0.0;
#pragma unroll
    for (int r = 0; r < 2; ++r) {
        const float4 ev = ev4[ll + r * 32];
        const float4 zv = zp[ll + r * 32];
        const double dx = (double)ev.x - zv.x, dy = (double)ev.y - zv.y;
        const double dz = (double)ev.z - zv.z, dw = (double)ev.w - zv.w;
        sm += dx * dx + dy * dy + dz * dz + dw * dw;
        zp[ll + r * 32] = ev;
    }
    for (int off = 32; off; off >>= 1) sm += __shfl_down(sm, off, 64);
    const int wid = t >> 6, lane = t & 63;
    if (lane == 0) wsum[wid] = sm;
    __syncthreads();
    if (t == 0) part[blockIdx.x] = (float)(wsum[0] + wsum[1] + wsum[2] + wsum[3]);
}

// ---------------------------------------------------------------- final diff reduction (f64)
__global__ __launch_bounds__(256) void k_final(const float* __restrict__ part,
                                               float* __restrict__ out_diff) {
    __shared__ double wsum[4];
    double sm = 0.0;
#pragma unroll
    for (int i = 0; i < 4; ++i) sm += (double)part[threadIdx.x + i * 256];
    for (int off = 32; off; off >>= 1) sm += __shfl_down(sm, off, 64);
    const int wid = threadIdx.x >> 6, lane = threadIdx.x & 63;
    if (lane == 0) wsum[wid] = sm;
    __syncthreads();
    if (threadIdx.x == 0)
        out_diff[0] = (float)(2.0 * (wsum[0] + wsum[1] + wsum[2] + wsum[3]) / 2097152.0);
}

extern "C" void kernel_launch(void* const* d_in, const int* in_sizes, int n_in,
                              void* d_out, int out_size, void* d_ws, size_t ws_size,
                              hipStream_t stream) {
    const float* z     = (const float*)d_in[0];
    const float* pw    = (const float*)d_in[1];
    const float* pb    = (const float*)d_in[2];
    const float* embed = (const float*)d_in[3];
    float* out = (float*)d_out;
    char*  ws  = (char*)d_ws;

    u64t*           amin  = (u64t*)(ws + WS_AMIN);
    float*          A     = (float*)(ws + WS_A);
    float*          Nf    = (float*)(ws + WS_N);
    unsigned*       e2    = (unsigned*)(ws + WS_EMAX);
    unsigned short* dlist = (unsigned short*)(ws + WS_DLIST);
    int*            dcnt  = (int*)(ws + WS_DCNT);
    float*          part  = (float*)(ws + WS_PART);

    float* ze       = out + OUT_ZQ;      // z_e lives in z_q slot, overwritten by gather
    float* out_diff = out + OUT_DIFF;
    float* out_ind  = out + OUT_IND;

    const bool big = (ws_size >= WS_BIG_END);

    k_init    <<<32,   256, 0, stream>>>(amin, dcnt, e2);
    k_ze_np   <<<512,  256, 0, stream>>>(z, pw, pb, ze);
    k_rowstats<<<64,   256, 0, stream>>>(ze, embed, A, Nf, e2);
    if (big) {
        int*            ccnt = (int*)(ws + WS_CCNT);
        unsigned*       cnd  = (unsigned*)(ws + WS_CND);
        u64t*           bq12 = (u64t*)(ws + WS_BQ);
        float*          b3v  = (float*)(ws + WS_B3V);
        unsigned short* zh3  = (unsigned short*)(ws + WS_ZH3);
        unsigned short* zl3  = (unsigned short*)(ws + WS_ZL3);
        unsigned short* eh3  = (unsigned short*)(ws + WS_EH3);
        unsigned short* el3  = (unsigned short*)(ws + WS_EL3);
        k_cvt  <<<2048, 256, 0, stream>>>(ze, embed, zh3, zl3, eh3, el3, ccnt);
        k_mfma <<<512,  256, 0, stream>>>(A, Nf, zh3, zl3, eh3, el3, bq12, b3v);
        k_sel  <<<32,   256, 0, stream>>>(A, bq12, b3v, dlist, dcnt, ccnt, cnd);
        k_cand <<<128,  256, 0, stream>>>(ze, embed, A, Nf, ccnt, cnd, amin);
        k_deep <<<2048, 256, 0, stream>>>(ze, embed, A, Nf, dlist, dcnt, amin);
    } else {
        k_dist_r10<<<1024, 256, 0, stream>>>(ze, embed, A, Nf, amin);
    }
    k_combine <<<32,   256, 0, stream>>>(amin, out_ind);
    k_gather  <<<1024, 256, 0, stream>>>(embed, out + OUT_ZQ, out_ind, part);
    k_final   <<<1,    256, 0, stream>>>(part, out_diff);
}

// Round 20
// 216.027 us; speedup vs baseline: 1.5038x; 1.0740x over previous
//
#include <hip/hip_runtime.h>

#define OUT_ZQ   0
#define OUT_DIFF 2097152
#define OUT_IND  2097153

// ws layout (bytes) — big path total 18,087,936
#define WS_AMIN   0        // u64[8192]
#define WS_A      65536    // f32[8192]
#define WS_N      98304    // f32[8192]
#define WS_EMAX   131072   // u32 (unused, kept for layout stability)
#define WS_DLIST  131136   // u16[4][8192] = 64 KB
#define WS_DCNT   196672   // i32[4]
#define WS_PART   196688   // f32[1024]
#define WS_CCNT   200784   // i32 (+pad)
#define WS_CND    200848   // u32[98304]
#define WS_BQ     594064   // u64[4][2][8192] = 512 KB  (top-2 keys per split)
#define WS_B3V    1118352  // f32[4][8192]              (3rd-best VALUE per split)
#define WS_ZH3    1310720  // u16[2M] = 4 MB  fragment-major hi(2*z_e)
#define WS_ZL3    5505024  // lo(2*z_e)
#define WS_EH3    9699328  // hi(embed)
#define WS_EL3    13893632 // lo(embed)
#define WS_BIG_END 18087936ULL
#define CAND_CAP  98304

typedef unsigned long long u64t;
typedef __attribute__((ext_vector_type(8))) short bf16x8;
typedef __attribute__((ext_vector_type(4))) float f32x4;

__device__ inline unsigned short bf16rn(float f) {
    unsigned u = __float_as_uint(f);
    return (unsigned short)((u + 0x7fffu + ((u >> 16) & 1u)) >> 16);
}
__device__ inline float bf16tof(unsigned short h) { return __uint_as_float(((unsigned)h) << 16); }
__device__ inline float valf(u64t k) { return __uint_as_float((unsigned)(k >> 32)); }

#define INITKEY ((((u64t)0x7F7FFFFFu) << 32) | 0xFFFFu)   // value = FLT_MAX (no NaN)

// ---------------------------------------------------------------- init (fallback path only)
__global__ __launch_bounds__(256) void k_init(u64t* __restrict__ amin) {
    amin[blockIdx.x * 256 + threadIdx.x] = ~0ULL;
}

// ---------------------------------------------------------------- z_e: bit-exact np.einsum replica (r15-proven v2)
__global__ __launch_bounds__(256) void k_ze_np(const float* __restrict__ z,
                                               const float* __restrict__ pw,
                                               const float* __restrict__ pb,
                                               float* __restrict__ ze) {
    __shared__ float lz[32][16];
    const int t   = threadIdx.x;
    const int b   = blockIdx.x >> 6;
    const int hw0 = (blockIdx.x & 63) * 16;

    float acc[16];
#pragma unroll
    for (int p = 0; p < 16; ++p) acc[p] = 0.0f;

    for (int cc = 0; cc < 256; cc += 32) {
        float4 wv[8];
        const float4* wsrc = reinterpret_cast<const float4*>(pw + (size_t)t * 256 + cc);
#pragma unroll
        for (int i = 0; i < 8; ++i) wv[i] = wsrc[i];
        float zv[2];
#pragma unroll
        for (int i = 0; i < 2; ++i) {
            const int f = t + i * 256;
            zv[i] = z[(size_t)(b * 256 + cc + (f >> 4)) * 1024 + hw0 + (f & 15)];
        }
        __syncthreads();
#pragma unroll
        for (int i = 0; i < 2; ++i) {
            const int f = t + i * 256;
            lz[f >> 4][f & 15] = zv[i];
        }
        __syncthreads();
#define ZSTEP(CL, WL) {                                                     \
    const float4 q0 = *reinterpret_cast<const float4*>(&lz[CL][0]);         \
    const float4 q1 = *reinterpret_cast<const float4*>(&lz[CL][4]);         \
    const float4 q2 = *reinterpret_cast<const float4*>(&lz[CL][8]);         \
    const float4 q3 = *reinterpret_cast<const float4*>(&lz[CL][12]);        \
    acc[0]  = __fadd_rn(acc[0],  __fmul_rn(q0.x, WL));                      \
    acc[1]  = __fadd_rn(acc[1],  __fmul_rn(q0.y, WL));                      \
    acc[2]  = __fadd_rn(acc[2],  __fmul_rn(q0.z, WL));                      \
    acc[3]  = __fadd_rn(acc[3],  __fmul_rn(q0.w, WL));                      \
    acc[4]  = __fadd_rn(acc[4],  __fmul_rn(q1.x, WL));                      \
    acc[5]  = __fadd_rn(acc[5],  __fmul_rn(q1.y, WL));                      \
    acc[6]  = __fadd_rn(acc[6],  __fmul_rn(q1.z, WL));                      \
    acc[7]  = __fadd_rn(acc[7],  __fmul_rn(q1.w, WL));                      \
    acc[8]  = __fadd_rn(acc[8],  __fmul_rn(q2.x, WL));                      \
    acc[9]  = __fadd_rn(acc[9],  __fmul_rn(q2.y, WL));                      \
    acc[10] = __fadd_rn(acc[10], __fmul_rn(q2.z, WL));                      \
    acc[11] = __fadd_rn(acc[11], __fmul_rn(q2.w, WL));                      \
    acc[12] = __fadd_rn(acc[12], __fmul_rn(q3.x, WL));                      \
    acc[13] = __fadd_rn(acc[13], __fmul_rn(q3.y, WL));                      \
    acc[14] = __fadd_rn(acc[14], __fmul_rn(q3.z, WL));                      \
    acc[15] = __fadd_rn(acc[15], __fmul_rn(q3.w, WL)); }
#pragma unroll
        for (int c8 = 0; c8 < 8; ++c8) {
            const float4 wq = wv[c8];
            ZSTEP(c8 * 4 + 0, wq.x)
            ZSTEP(c8 * 4 + 1, wq.y)
            ZSTEP(c8 * 4 + 2, wq.z)
            ZSTEP(c8 * 4 + 3, wq.w)
        }
#undef ZSTEP
    }
    const float bb = pb[t];
#pragma unroll
    for (int p = 0; p < 16; ++p)
        ze[(size_t)(b * 1024 + hw0 + p) * 256 + t] = __fadd_rn(acc[p], bb);
}

// ---------------------------------------------------------------- np pairwise row-norms
__global__ __launch_bounds__(256) void k_rowstats(const float* __restrict__ ze,
                                                  const float* __restrict__ embed,
                                                  float* __restrict__ A,
                                                  float* __restrict__ Nf) {
    const int gid = blockIdx.x * 256 + threadIdx.x;
    const float* row = (gid < 8192) ? (ze + (size_t)gid * 256)
                                    : (embed + (size_t)(gid - 8192) * 256);
    float blk[2];
#pragma unroll
    for (int half = 0; half < 2; ++half) {
        const float4* r4 = reinterpret_cast<const float4*>(row + half * 128);
        float r[8];
#pragma unroll
        for (int i = 0; i < 16; ++i) {
            const float4 a = r4[i * 2], b = r4[i * 2 + 1];
            const float s[8] = {__fmul_rn(a.x, a.x), __fmul_rn(a.y, a.y),
                                __fmul_rn(a.z, a.z), __fmul_rn(a.w, a.w),
                                __fmul_rn(b.x, b.x), __fmul_rn(b.y, b.y),
                                __fmul_rn(b.z, b.z), __fmul_rn(b.w, b.w)};
            if (i == 0) {
#pragma unroll
                for (int j = 0; j < 8; ++j) r[j] = s[j];
            } else {
#pragma unroll
                for (int j = 0; j < 8; ++j) r[j] = __fadd_rn(r[j], s[j]);
            }
        }
        blk[half] = __fadd_rn(__fadd_rn(__fadd_rn(r[0], r[1]), __fadd_rn(r[2], r[3])),
                              __fadd_rn(__fadd_rn(r[4], r[5]), __fadd_rn(r[6], r[7])));
    }
    const float res = __fadd_rn(blk[0], blk[1]);
    if (gid < 8192) A[gid] = res;
    else            Nf[gid - 8192] = res;
}

// ---------------------------------------------------------------- bf16 hi/lo precompute in FRAGMENT-MAJOR layout
// Also initializes amin/dcnt/ccnt (replaces k_init in the big path; runs before all consumers).
__global__ __launch_bounds__(256) void k_cvt(const float* __restrict__ ze,
                                             const float* __restrict__ embed,
                                             unsigned short* __restrict__ zh3,
                                             unsigned short* __restrict__ zl3,
                                             unsigned short* __restrict__ eh3,
                                             unsigned short* __restrict__ el3,
                                             int* __restrict__ ccnt,
                                             u64t* __restrict__ amin,
                                             int* __restrict__ dcnt) {
    const int gid = blockIdx.x * 256 + threadIdx.x;
    if (gid == 0) *ccnt = 0;
    if (gid < 4) dcnt[gid] = 0;
    const int row = gid >> 5;
    const int c0  = (gid & 31) * 8;
    if ((gid & 31) == 0 && row < 8192) amin[row] = ~0ULL;
    const bool isz = (row < 8192);
    const float* src = (isz ? ze + (size_t)row * 256 : embed + (size_t)(row - 8192) * 256) + c0;
    const float4 v0 = reinterpret_cast<const float4*>(src)[0];
    const float4 v1 = reinterpret_cast<const float4*>(src)[1];
    float x[8] = {v0.x, v0.y, v0.z, v0.w, v1.x, v1.y, v1.z, v1.w};
    if (isz) {
#pragma unroll
        for (int i = 0; i < 8; ++i) x[i] = __fmul_rn(2.0f, x[i]);   // exact prescale
    }
    unsigned short hv[8], lv[8];
#pragma unroll
    for (int i = 0; i < 8; ++i) {
        hv[i] = bf16rn(x[i]);
        lv[i] = bf16rn(__fsub_rn(x[i], bf16tof(hv[i])));
    }
    const int ci = c0 >> 5, lg = (c0 >> 3) & 3;
    if (isz) {
        const int pt = row >> 6, ti = (row >> 4) & 3, lr = row & 15;
        const int lane = lg * 16 + lr;
        const size_t off = ((size_t)(ci * 128 + pt) * 4 + ti) * 512 + (size_t)lane * 8;
        *reinterpret_cast<ushort4*>(zh3 + off)     = make_ushort4(hv[0], hv[1], hv[2], hv[3]);
        *reinterpret_cast<ushort4*>(zh3 + off + 4) = make_ushort4(hv[4], hv[5], hv[6], hv[7]);
        *reinterpret_cast<ushort4*>(zl3 + off)     = make_ushort4(lv[0], lv[1], lv[2], lv[3]);
        *reinterpret_cast<ushort4*>(zl3 + off + 4) = make_ushort4(lv[4], lv[5], lv[6], lv[7]);
    } else {
        const int k = row - 8192;
        const int ks = k >> 11, ksub = (k >> 8) & 7, w = (k >> 6) & 3, tj = (k >> 4) & 3, lr = k & 15;
        const int lane = lg * 16 + lr;
        const size_t off = (((size_t)((ks * 8 + ksub) * 8 + ci) * 16) + w * 4 + tj) * 512 + (size_t)lane * 8;
        *reinterpret_cast<ushort4*>(eh3 + off)     = make_ushort4(hv[0], hv[1], hv[2], hv[3]);
        *reinterpret_cast<ushort4*>(eh3 + off + 4) = make_ushort4(hv[4], hv[5], hv[6], hv[7]);
        *reinterpret_cast<ushort4*>(el3 + off)     = make_ushort4(lv[0], lv[1], lv[2], lv[3]);
        *reinterpret_cast<ushort4*>(el3 + off + 4) = make_ushort4(lv[4], lv[5], lv[6], lv[7]);
    }
}

// ---------------------------------------------------------------- MFMA screen v3 + setprio around MFMA cluster
__global__ __launch_bounds__(256, 2) void k_mfma(const float* __restrict__ A,
                                                 const float* __restrict__ Nf,
                                                 const unsigned short* __restrict__ zh3,
                                                 const unsigned short* __restrict__ zl3,
                                                 const unsigned short* __restrict__ eh3,
                                                 const unsigned short* __restrict__ el3,
                                                 u64t* __restrict__ bq12,
                                                 float* __restrict__ b3v) {
    __shared__ u64t  mrgk[64][4][2];
    __shared__ float mrgv[64][4];
    const int t = threadIdx.x;
    const int ks = blockIdx.x & 3, pt = blockIdx.x >> 2;
    const int pix0 = pt * 64;
    const int w = t >> 6, l = t & 63;
    const int lg = l >> 4, lr = l & 15;

    float a_reg[4][4];
#pragma unroll
    for (int ti = 0; ti < 4; ++ti)
#pragma unroll
        for (int r = 0; r < 4; ++r)
            a_reg[ti][r] = A[pix0 + ti * 16 + lg * 4 + r];

    u64t b1[4][4], b2[4][4];
    float bv[4][4];
#pragma unroll
    for (int ti = 0; ti < 4; ++ti)
#pragma unroll
        for (int r = 0; r < 4; ++r) { b1[ti][r] = INITKEY; b2[ti][r] = INITKEY; bv[ti][r] = 3.402823466e+38f; }

    const size_t zoff0 = (size_t)pt * 2048 + (size_t)l * 8;
    for (int ksub = 0; ksub < 8; ++ksub) {
        f32x4 acc[4][4];
#pragma unroll
        for (int ti = 0; ti < 4; ++ti)
#pragma unroll
            for (int tj = 0; tj < 4; ++tj) acc[ti][tj] = (f32x4)(0.0f);

        const size_t ebase = (size_t)(ks * 8 + ksub) * 65536 + (size_t)w * 2048 + (size_t)l * 8;
#pragma unroll 2
        for (int ci = 0; ci < 8; ++ci) {
            const size_t zo = zoff0 + (size_t)ci * 262144;
            const size_t eo = ebase + (size_t)ci * 8192;
            bf16x8 az[4], alz[4], be[4], ble[4];
#pragma unroll
            for (int ti = 0; ti < 4; ++ti) {
                az[ti]  = *reinterpret_cast<const bf16x8*>(zh3 + zo + (size_t)ti * 512);
                alz[ti] = *reinterpret_cast<const bf16x8*>(zl3 + zo + (size_t)ti * 512);
            }
#pragma unroll
            for (int tj = 0; tj < 4; ++tj) {
                be[tj]  = *reinterpret_cast<const bf16x8*>(eh3 + eo + (size_t)tj * 512);
                ble[tj] = *reinterpret_cast<const bf16x8*>(el3 + eo + (size_t)tj * 512);
            }
            __builtin_amdgcn_s_setprio(1);
#pragma unroll
            for (int tj = 0; tj < 4; ++tj)
#pragma unroll
                for (int ti = 0; ti < 4; ++ti) {
                    acc[ti][tj] = __builtin_amdgcn_mfma_f32_16x16x32_bf16(az[ti],  be[tj],  acc[ti][tj], 0, 0, 0);
                    acc[ti][tj] = __builtin_amdgcn_mfma_f32_16x16x32_bf16(az[ti],  ble[tj], acc[ti][tj], 0, 0, 0);
                    acc[ti][tj] = __builtin_amdgcn_mfma_f32_16x16x32_bf16(alz[ti], be[tj],  acc[ti][tj], 0, 0, 0);
                }
            __builtin_amdgcn_s_setprio(0);
        }
#pragma unroll
        for (int tj = 0; tj < 4; ++tj) {
            const int kk = ks * 2048 + ksub * 256 + w * 64 + tj * 16 + lr;
            const float nk = Nf[kk];
#pragma unroll
            for (int ti = 0; ti < 4; ++ti)
#pragma unroll
                for (int r = 0; r < 4; ++r) {
                    const float vv = __fadd_rn(__fsub_rn(a_reg[ti][r], acc[ti][tj][r]), nk);
                    const u64t key = ((u64t)__float_as_uint(vv) << 32) | (unsigned)kk;
                    if (key < b2[ti][r]) {
                        bv[ti][r] = valf(b2[ti][r]);
                        if (key < b1[ti][r]) { b2[ti][r] = b1[ti][r]; b1[ti][r] = key; }
                        else                 { b2[ti][r] = key; }
                    } else {
                        bv[ti][r] = fminf(bv[ti][r], vv);
                    }
                }
        }
    }
#pragma unroll
    for (int ti = 0; ti < 4; ++ti)
#pragma unroll
        for (int r = 0; r < 4; ++r) {
            u64t k1 = b1[ti][r], k2 = b2[ti][r];
            float v3 = bv[ti][r];
#pragma unroll
            for (int m = 1; m <= 8; m <<= 1) {
                const u64t o1 = __shfl_xor(k1, m, 64);
                const u64t o2 = __shfl_xor(k2, m, 64);
                const float ov = __shfl_xor(v3, m, 64);
                const u64t n1 = (k1 < o1) ? k1 : o1;
                const u64t X  = (k1 < o1) ? o1 : k1;
                const u64t Y  = (k2 < o2) ? k2 : o2;
                const u64t n2 = (X < Y) ? X : Y;
                const u64t t4 = (X < Y) ? Y : X;
                v3 = fminf(fminf(v3, ov), valf(t4));
                k1 = n1; k2 = n2;
            }
            b1[ti][r] = k1; b2[ti][r] = k2; bv[ti][r] = v3;
        }
    if (lr == 0) {
#pragma unroll
        for (int ti = 0; ti < 4; ++ti)
#pragma unroll
            for (int r = 0; r < 4; ++r) {
                const int pxl = ti * 16 + lg * 4 + r;
                mrgk[pxl][w][0] = b1[ti][r];
                mrgk[pxl][w][1] = b2[ti][r];
                mrgv[pxl][w]    = bv[ti][r];
            }
    }
    __syncthreads();
    if (t < 64) {
        u64t K1 = INITKEY, K2 = INITKEY;
        float V3 = 3.402823466e+38f;
#pragma unroll
        for (int w4 = 0; w4 < 4; ++w4) {
            const u64t o1 = mrgk[t][w4][0], o2 = mrgk[t][w4][1];
            const float ov = mrgv[t][w4];
            const u64t n1 = (K1 < o1) ? K1 : o1;
            const u64t X  = (K1 < o1) ? o1 : K1;
            const u64t Y  = (K2 < o2) ? K2 : o2;
            const u64t n2 = (X < Y) ? X : Y;
            const u64t t4 = (X < Y) ? Y : X;
            V3 = fminf(fminf(V3, ov), valf(t4));
            K1 = n1; K2 = n2;
        }
        bq12[((size_t)(ks * 2 + 0)) * 8192 + pix0 + t] = K1;
        bq12[((size_t)(ks * 2 + 1)) * 8192 + pix0 + t] = K2;
        b3v[(size_t)ks * 8192 + pix0 + t] = V3;
    }
}

// ---------------------------------------------------------------- select: candidates + deep flags (3rd-VALUE gated)
__global__ __launch_bounds__(256) void k_sel(const float* __restrict__ A,
                                             const u64t* __restrict__ bq12,
                                             const float* __restrict__ b3v,
                                             unsigned short* __restrict__ dlist,
                                             int* __restrict__ dcnt,
                                             int* __restrict__ ccnt,
                                             unsigned* __restrict__ cnd) {
    const int px = blockIdx.x * 256 + threadIdx.x;
    const int lane = threadIdx.x & 63;
    u64t k1[4], k2[4];
    float v3[4];
#pragma unroll
    for (int s = 0; s < 4; ++s) {
        k1[s] = bq12[((size_t)(s * 2 + 0)) * 8192 + px];
        k2[s] = bq12[((size_t)(s * 2 + 1)) * 8192 + px];
        v3[s] = b3v[(size_t)s * 8192 + px];
    }
    float m = valf(k1[0]);
#pragma unroll
    for (int s = 1; s < 4; ++s) m = fminf(m, valf(k1[s]));
    const float a = A[px];
    const unsigned eb = (__float_as_uint(a + 0.125f) >> 23) & 255u;
    const float up = __uint_as_float((eb - 23u) << 23);
    const float thresh = m + 4.5f * up + 1.0e-5f;

    unsigned cand[8];
    int nc = 0;
#pragma unroll
    for (int s = 0; s < 4; ++s) {
        if (valf(k1[s]) <= thresh) cand[nc++] = ((unsigned)px << 16) | (unsigned)(k1[s] & 0xffffu);
        if (valf(k2[s]) <= thresh) cand[nc++] = ((unsigned)px << 16) | (unsigned)(k2[s] & 0xffffu);
        if (v3[s] <= thresh) {
            const int pos = atomicAdd(&dcnt[s], 1);
            if (pos < 8192) dlist[s * 8192 + pos] = (unsigned short)px;
        }
    }
    int sc = nc;
#pragma unroll
    for (int o = 1; o < 64; o <<= 1) {
        const int n = __shfl_up(sc, o, 64);
        if (lane >= o) sc += n;
    }
    int base = 0;
    if (lane == 63) base = atomicAdd(ccnt, sc);
    base = __shfl(base, 63, 64);
    const int off = base + sc - nc;
    for (int j = 0; j < nc; ++j)
        if (off + j < CAND_CAP) cnd[off + j] = cand[j];
}

// ---------------------------------------------------------------- candidate np-exact rescore
__global__ __launch_bounds__(256) void k_cand(const float* __restrict__ ze,
                                              const float* __restrict__ embed,
                                              const float* __restrict__ A,
                                              const float* __restrict__ Nf,
                                              const int* __restrict__ ccnt,
                                              const unsigned* __restrict__ cnd,
                                              u64t* __restrict__ amin) {
    int cnt = *ccnt; if (cnt > CAND_CAP) cnt = CAND_CAP;
    for (int i = blockIdx.x * 256 + threadIdx.x; i < cnt; i += 32768) {
        const unsigned pk = cnd[i];
        const int px = pk >> 16, k = pk & 0xffffu;
        const float4* zr = reinterpret_cast<const float4*>(ze + (size_t)px * 256);
        const float4* er = reinterpret_cast<const float4*>(embed + (size_t)k * 256);
        float acc = 0.0f;
        for (int c4 = 0; c4 < 64; ++c4) {
            const float4 z4 = zr[c4], e4 = er[c4];
            acc = fmaf(__fmul_rn(2.0f, z4.x), e4.x, acc);
            acc = fmaf(__fmul_rn(2.0f, z4.y), e4.y, acc);
            acc = fmaf(__fmul_rn(2.0f, z4.z), e4.z, acc);
            acc = fmaf(__fmul_rn(2.0f, z4.w), e4.w, acc);
        }
        const float v = __fadd_rn(__fsub_rn(A[px], acc), Nf[k]);
        atomicMin(&amin[px], ((u64t)__float_as_uint(v) << 32) | (unsigned)k);
    }
}

// ---------------------------------------------------------------- deep v3: one block per (flagged px, 256-k slice)
__global__ __launch_bounds__(256) void k_deep(const float* __restrict__ ze,
                                              const float* __restrict__ embed,
                                              const float* __restrict__ A,
                                              const float* __restrict__ Nf,
                                              const unsigned short* __restrict__ dlist,
                                              const int* __restrict__ dcnt,
                                              u64t* __restrict__ amin) {
    __shared__ float lz2[256];
    __shared__ float sa[1];
    __shared__ u64t lw4[4];
    const int t = threadIdx.x;
    int n0 = dcnt[0], n1 = dcnt[1], n2 = dcnt[2], n3 = dcnt[3];
    n0 = (n0 > 8192) ? 8192 : n0;  n1 = (n1 > 8192) ? 8192 : n1;
    n2 = (n2 > 8192) ? 8192 : n2;  n3 = (n3 > 8192) ? 8192 : n3;
    const int tot = (n0 + n1 + n2 + n3) * 8;

    for (int it = blockIdx.x; it < tot; it += gridDim.x) {
        const int q = it >> 3, slice = it & 7;
        int s, pxi;
        if (q < n0)                { s = 0; pxi = q; }
        else if (q < n0 + n1)      { s = 1; pxi = q - n0; }
        else if (q < n0 + n1 + n2) { s = 2; pxi = q - n0 - n1; }
        else                       { s = 3; pxi = q - n0 - n1 - n2; }
        const int px = dlist[s * 8192 + pxi];

        __syncthreads();   // protect lz2/lw4 from previous iteration's readers
        lz2[t] = __fmul_rn(2.0f, ze[(size_t)px * 256 + t]);   // exact prescale
        if (t == 0) sa[0] = A[px];
        __syncthreads();

        const int k = s * 2048 + slice * 256 + t;
        const float4* er = reinterpret_cast<const float4*>(embed + (size_t)k * 256);
        float acc = 0.0f;
#pragma unroll 8
        for (int c4 = 0; c4 < 64; ++c4) {
            const float4 e4 = er[c4];
            acc = fmaf(lz2[c4 * 4 + 0], e4.x, acc);
            acc = fmaf(lz2[c4 * 4 + 1], e4.y, acc);
            acc = fmaf(lz2[c4 * 4 + 2], e4.z, acc);
            acc = fmaf(lz2[c4 * 4 + 3], e4.w, acc);
        }
        const float v = __fadd_rn(__fsub_rn(sa[0], acc), Nf[k]);
        u64t key = ((u64t)__float_as_uint(v) << 32) | (unsigned)k;
#pragma unroll
        for (int m = 1; m <= 32; m <<= 1) {
            const u64t o = __shfl_xor(key, m, 64);
            key = (o < key) ? o : key;
        }
        if ((t & 63) == 0) lw4[t >> 6] = key;
        __syncthreads();
        if (t == 0) {
            u64t bk = lw4[0];
            bk = (lw4[1] < bk) ? lw4[1] : bk;
            bk = (lw4[2] < bk) ? lw4[2] : bk;
            bk = (lw4[3] < bk) ? lw4[3] : bk;
            atomicMin(&amin[px], bk);
        }
    }
}

// ---------------------------------------------------------------- fallback (ws too small): r10 VALU distance kernel
__global__ __launch_bounds__(256, 2) void k_dist_r10(const float* __restrict__ ze,
                                                     const float* __restrict__ embed,
                                                     const float* __restrict__ A,
                                                     const float* __restrict__ Nf,
                                                     u64t* __restrict__ amin) {
    __shared__ __align__(16) char smem[49152];
    float (*le)[128] = reinterpret_cast<float (*)[128]>(smem);
    float (*z2)[256] = reinterpret_cast<float (*)[256]>(smem + 16384);
    u64t* red = reinterpret_cast<u64t*>(smem);

    const int t    = threadIdx.x;
    const int ks   = blockIdx.x & 31;
    const int pt   = blockIdx.x >> 5;
    const int pix0 = pt * 256;
    const int k0   = ks * 256;
    const int tp   = t & 15, tk = t >> 4;
    const int er   = t >> 1, eh2 = (t & 1) * 16;

    float best[16];
    int   bidx[16];
#pragma unroll
    for (int i = 0; i < 16; ++i) { best[i] = 3.402823466e+38f; bidx[i] = 0x7fffffff; }

    float Ai[16];
#pragma unroll
    for (int q = 0; q < 4; ++q)
#pragma unroll
        for (int m = 0; m < 4; ++m)
            Ai[q * 4 + m] = A[pix0 + (q * 16 + tp) * 4 + m];

    for (int kc = 0; kc < 256; kc += 128) {
        float acc[16][8];
#pragma unroll
        for (int i = 0; i < 16; ++i)
#pragma unroll
            for (int j = 0; j < 8; ++j) acc[i][j] = 0.0f;
        const int kbase = k0 + kc + tk * 8;
        for (int cc = 0; cc < 256; cc += 32) {
            float4 se[4], sz[8];
            const float4* esrc = reinterpret_cast<const float4*>(
                embed + (size_t)(k0 + kc + er) * 256 + cc + eh2);
#pragma unroll
            for (int m = 0; m < 4; ++m) se[m] = esrc[m];
            const float4* zsrc = reinterpret_cast<const float4*>(
                ze + (size_t)(pix0 + t) * 256 + cc);
#pragma unroll
            for (int m = 0; m < 8; ++m) sz[m] = zsrc[m];
            __syncthreads();
#pragma unroll
            for (int m = 0; m < 4; ++m) {
                le[eh2 + m * 4 + 0][er] = se[m].x;
                le[eh2 + m * 4 + 1][er] = se[m].y;
                le[eh2 + m * 4 + 2][er] = se[m].z;
                le[eh2 + m * 4 + 3][er] = se[m].w;
            }
#pragma unroll
            for (int m = 0; m < 8; ++m) {
                z2[m * 4 + 0][t] = __fmul_rn(2.0f, sz[m].x);
                z2[m * 4 + 1][t] = __fmul_rn(2.0f, sz[m].y);
                z2[m * 4 + 2][t] = __fmul_rn(2.0f, sz[m].z);
                z2[m * 4 + 3][t] = __fmul_rn(2.0f, sz[m].w);
            }
            __syncthreads();
#pragma unroll 2
            for (int c = 0; c < 32; ++c) {
                const float4 e0 = *reinterpret_cast<const float4*>(&le[c][tk * 8]);
                const float4 e1 = *reinterpret_cast<const float4*>(&le[c][tk * 8 + 4]);
                float4 zq[4];
#pragma unroll
                for (int q = 0; q < 4; ++q)
                    zq[q] = *reinterpret_cast<const float4*>(&z2[c][(q * 16 + tp) * 4]);
#define FMA8(i, zv)                                          \
    acc[i][0] = fmaf(zv, e0.x, acc[i][0]);                   \
    acc[i][1] = fmaf(zv, e0.y, acc[i][1]);                   \
    acc[i][2] = fmaf(zv, e0.z, acc[i][2]);                   \
    acc[i][3] = fmaf(zv, e0.w, acc[i][3]);                   \
    acc[i][4] = fmaf(zv, e1.x, acc[i][4]);                   \
    acc[i][5] = fmaf(zv, e1.y, acc[i][5]);                   \
    acc[i][6] = fmaf(zv, e1.z, acc[i][6]);                   \
    acc[i][7] = fmaf(zv, e1.w, acc[i][7]);
#pragma unroll
                for (int q = 0; q < 4; ++q) {
                    FMA8(q * 4 + 0, zq[q].x)
                    FMA8(q * 4 + 1, zq[q].y)
                    FMA8(q * 4 + 2, zq[q].z)
                    FMA8(q * 4 + 3, zq[q].w)
                }
#undef FMA8
            }
        }
        const float4 n0 = *reinterpret_cast<const float4*>(&Nf[kbase]);
        const float4 n1 = *reinterpret_cast<const float4*>(&Nf[kbase + 4]);
        const float nk[8] = {n0.x, n0.y, n0.z, n0.w, n1.x, n1.y, n1.z, n1.w};
#pragma unroll
        for (int j = 0; j < 8; ++j) {
            const int k = kbase + j;
#pragma unroll
            for (int i = 0; i < 16; ++i) {
                const float v = __fadd_rn(__fsub_rn(Ai[i], acc[i][j]), nk[j]);
                if (v < best[i]) { best[i] = v; bidx[i] = k; }
            }
        }
    }
    __syncthreads();
#pragma unroll
    for (int i = 0; i < 16; ++i) {
        const int px = ((i >> 2) * 16 + tp) * 4 + (i & 3);
        const unsigned u = __float_as_uint(best[i]);
        red[px * 17 + tk] = ((u64t)u << 32) | (unsigned)bidx[i];
    }
    __syncthreads();
    {
        u64t bvv = ~0ULL;
#pragma unroll 4
        for (int q2 = 0; q2 < 16; ++q2) {
            const u64t v = red[t * 17 + q2];
            bvv = (v < bvv) ? v : bvv;
        }
        atomicMin(&amin[pix0 + t], bvv);
    }
}

// ---------------------------------------------------------------- gather z_q + out_ind (from amin) + partial MSE (f64)
__global__ __launch_bounds__(256) void k_gather(const float* __restrict__ embed,
                                                float* __restrict__ out,
                                                const u64t* __restrict__ amin,
                                                float* __restrict__ out_ind,
                                                float* __restrict__ part) {
    __shared__ double wsum[4];
    const int t = threadIdx.x;
    const int g = t >> 5, ll = t & 31;
    const int nn = blockIdx.x * 8 + g;
    const int idx = (int)(unsigned)(amin[nn] & 0xffffffffULL);
    if (ll == 0) out_ind[nn] = (float)idx;
    const float4* ev4 = reinterpret_cast<const float4*>(embed + (size_t)idx * 256);
    float4* zp = reinterpret_cast<float4*>(out + (size_t)nn * 256);
    double sm = 0.0;
#pragma unroll
    for (int r = 0; r < 2; ++r) {
        const float4 ev = ev4[ll + r * 32];
        const float4 zv = zp[ll + r * 32];
        const double dx = (double)ev.x - zv.x, dy = (double)ev.y - zv.y;
        const double dz = (double)ev.z - zv.z, dw = (double)ev.w - zv.w;
        sm += dx * dx + dy * dy + dz * dz + dw * dw;
        zp[ll + r * 32] = ev;
    }
    for (int off = 32; off; off >>= 1) sm += __shfl_down(sm, off, 64);
    const int wid = t >> 6, lane = t & 63;
    if (lane == 0) wsum[wid] = sm;
    __syncthreads();
    if (t == 0) part[blockIdx.x] = (float)(wsum[0] + wsum[1] + wsum[2] + wsum[3]);
}

// ---------------------------------------------------------------- final diff reduction (f64)
__global__ __launch_bounds__(256) void k_final(const float* __restrict__ part,
                                               float* __restrict__ out_diff) {
    __shared__ double wsum[4];
    double sm = 0.0;
#pragma unroll
    for (int i = 0; i < 4; ++i) sm += (double)part[threadIdx.x + i * 256];
    for (int off = 32; off; off >>= 1) sm += __shfl_down(sm, off, 64);
    const int wid = threadIdx.x >> 6, lane = threadIdx.x & 63;
    if (lane == 0) wsum[wid] = sm;
    __syncthreads();
    if (threadIdx.x == 0)
        out_diff[0] = (float)(2.0 * (wsum[0] + wsum[1] + wsum[2] + wsum[3]) / 2097152.0);
}

extern "C" void kernel_launch(void* const* d_in, const int* in_sizes, int n_in,
                              void* d_out, int out_size, void* d_ws, size_t ws_size,
                              hipStream_t stream) {
    const float* z     = (const float*)d_in[0];
    const float* pw    = (const float*)d_in[1];
    const float* pb    = (const float*)d_in[2];
    const float* embed = (const float*)d_in[3];
    float* out = (float*)d_out;
    char*  ws  = (char*)d_ws;

    u64t*           amin  = (u64t*)(ws + WS_AMIN);
    float*          A     = (float*)(ws + WS_A);
    float*          Nf    = (float*)(ws + WS_N);
    unsigned short* dlist = (unsigned short*)(ws + WS_DLIST);
    int*            dcnt  = (int*)(ws + WS_DCNT);
    float*          part  = (float*)(ws + WS_PART);

    float* ze       = out + OUT_ZQ;      // z_e lives in z_q slot, overwritten by gather
    float* out_diff = out + OUT_DIFF;
    float* out_ind  = out + OUT_IND;

    const bool big = (ws_size >= WS_BIG_END);

    k_ze_np   <<<512,  256, 0, stream>>>(z, pw, pb, ze);
    k_rowstats<<<64,   256, 0, stream>>>(ze, embed, A, Nf);
    if (big) {
        int*            ccnt = (int*)(ws + WS_CCNT);
        unsigned*       cnd  = (unsigned*)(ws + WS_CND);
        u64t*           bq12 = (u64t*)(ws + WS_BQ);
        float*          b3v  = (float*)(ws + WS_B3V);
        unsigned short* zh3  = (unsigned short*)(ws + WS_ZH3);
        unsigned short* zl3  = (unsigned short*)(ws + WS_ZL3);
        unsigned short* eh3  = (unsigned short*)(ws + WS_EH3);
        unsigned short* el3  = (unsigned short*)(ws + WS_EL3);
        k_cvt  <<<2048, 256, 0, stream>>>(ze, embed, zh3, zl3, eh3, el3, ccnt, amin, dcnt);
        k_mfma <<<512,  256, 0, stream>>>(A, Nf, zh3, zl3, eh3, el3, bq12, b3v);
        k_sel  <<<32,   256, 0, stream>>>(A, bq12, b3v, dlist, dcnt, ccnt, cnd);
        k_cand <<<128,  256, 0, stream>>>(ze, embed, A, Nf, ccnt, cnd, amin);
        k_deep <<<2048, 256, 0, stream>>>(ze, embed, A, Nf, dlist, dcnt, amin);
    } else {
        k_init    <<<32,   256, 0, stream>>>(amin);
        k_dist_r10<<<1024, 256, 0, stream>>>(ze, embed, A, Nf, amin);
    }
    k_gather  <<<1024, 256, 0, stream>>>(embed, out + OUT_ZQ, amin, out_ind, part);
    k_final   <<<1,    256, 0, stream>>>(part, out_diff);
}